// Round 5
// baseline (869.239 us; speedup 1.0000x reference)
//
#include <hip/hip_runtime.h>
#include <stdint.h>

typedef __attribute__((ext_vector_type(8))) short bf16x8;
typedef __attribute__((ext_vector_type(4))) float f32x4;

__device__ __forceinline__ float bf2f(ushort h) {
    union { uint u; float f; } v; v.u = ((uint)h) << 16; return v.f;
}
__device__ __forceinline__ ushort f2bf(float f) {
    union { float f; uint u; } v; v.f = f;
    uint u = v.u;
    return (ushort)((u + 0x7fffu + ((u >> 16) & 1u)) >> 16);
}

// async global->LDS, 16B per lane; LDS dest = wave-uniform base + lane*16
__device__ __forceinline__ void gll(const ushort* g, ushort* l) {
    __builtin_amdgcn_global_load_lds(
        (const __attribute__((address_space(1))) void*)g,
        (__attribute__((address_space(3))) void*)l, 16, 0, 0);
}

// ---------------- graph prep ----------------

__global__ void k_group(const uint4* __restrict__ x4, const uint4* __restrict__ nf4, int NN,
                        int* __restrict__ gid, int* __restrict__ gcnt) {
    __shared__ int cnt[4];
    if (threadIdx.x < 4) cnt[threadIdx.x] = 0;
    __syncthreads();
    int i = blockIdx.x * blockDim.x + threadIdx.x;
    if (i < NN) {
        const uint4* xr = x4 + (size_t)i * 25;  // 100 floats = 25 uint4
        bool e0 = true, e1 = true, e2 = true;
#pragma unroll 5
        for (int d = 0; d < 25; ++d) {
            uint4 v = xr[d];
            uint4 a = nf4[d], b = nf4[25 + d], c = nf4[50 + d];
            e0 &= (v.x == a.x) & (v.y == a.y) & (v.z == a.z) & (v.w == a.w);
            e1 &= (v.x == b.x) & (v.y == b.y) & (v.z == b.z) & (v.w == b.w);
            e2 &= (v.x == c.x) & (v.y == c.y) & (v.z == c.z) & (v.w == c.w);
        }
        int g = e0 ? 0 : (e1 ? 3 : (e2 ? 1 : 2));
        gid[i] = g;
        atomicAdd(&cnt[g], 1);
    }
    __syncthreads();
    if (threadIdx.x < 4 && cnt[threadIdx.x]) atomicAdd(&gcnt[threadIdx.x], cnt[threadIdx.x]);
}

__global__ void k_deg(const int* __restrict__ src, const int* __restrict__ dst,
                      const int* __restrict__ gid, int E,
                      int* __restrict__ deg, int* __restrict__ deg2) {
    int e = blockIdx.x * blockDim.x + threadIdx.x;
    if (e >= E) return;
    int d = dst[e];
    atomicAdd(&deg[d], 1);
    if (gid[src[e]] == 2) atomicAdd(&deg2[d], 1);
}

__global__ void k_dinv(const int* __restrict__ deg, float* __restrict__ dinv, int NN) {
    int i = blockIdx.x * blockDim.x + threadIdx.x;
    if (i < NN) dinv[i] = 1.0f / sqrtf((float)(deg[i] + 1));  // +1 self loop
}

__global__ void k_scan(const int* __restrict__ deg, int* __restrict__ offs, int NN) {
    __shared__ int lds[1024];
    int t = threadIdx.x;
    int chunk = (NN + 1023) / 1024;
    int b0 = t * chunk;
    int b1 = min(b0 + chunk, NN);
    int s = 0;
    for (int i = b0; i < b1; ++i) s += deg[i];
    lds[t] = s;
    __syncthreads();
    for (int d = 1; d < 1024; d <<= 1) {
        int v = (t >= d) ? lds[t - d] : 0;
        __syncthreads();
        lds[t] += v;
        __syncthreads();
    }
    int excl = (t == 0) ? 0 : lds[t - 1];
    for (int i = b0; i < b1; ++i) { offs[i] = excl; excl += deg[i]; }
}

// Fill full CSR (packed {src, w}); route proto-src edges of layer-1 into
// per-(dst,group) weight sums, others into reduced CSR2.
__global__ void k_fill(const int* __restrict__ src, const int* __restrict__ dst, int E,
                       const float* __restrict__ dinv, const int* __restrict__ gid,
                       const int* __restrict__ offs, int* __restrict__ cur, uint2* __restrict__ epk,
                       const int* __restrict__ offs2, int* __restrict__ cur2, uint2* __restrict__ epk2,
                       float* __restrict__ protoW) {
    int e = blockIdx.x * blockDim.x + threadIdx.x;
    if (e >= E) return;
    int s = src[e], d = dst[e];
    float w = dinv[s] * dinv[d];
    int p = offs[d] + atomicAdd(&cur[d], 1);
    epk[p] = make_uint2((uint)s, __float_as_uint(w));
    int g = gid[s];
    if (g == 2) {
        int q = offs2[d] + atomicAdd(&cur2[d], 1);
        epk2[q] = make_uint2((uint)s, __float_as_uint(w));
    } else {
        atomicAdd(&protoW[d * 4 + g], w);
    }
}

// ---------------- aggregation (gather, wave per node) ----------------

template <int D, int DPAD, bool BR, bool SPLIT>
__global__ void k_agg(const float* __restrict__ H,
                      float* __restrict__ outf, ushort* __restrict__ outh, ushort* __restrict__ outl,
                      const float* __restrict__ dinv, const int* __restrict__ offs,
                      const int* __restrict__ deg, const uint2* __restrict__ epk,
                      const float* __restrict__ bias,
                      int NN, int NNpad) {
    int wid = (int)((blockIdx.x * blockDim.x + threadIdx.x) >> 6);
    int lane = threadIdx.x & 63;
    if (wid >= NNpad) return;
    constexpr int VEC = DPAD / 64;
    int c0 = lane * VEC;
    if (wid >= NN) {  // zero pad rows so GEMM A-tiles are clean
#pragma unroll
        for (int j = 0; j < VEC; ++j) {
            if (SPLIT) { outh[(size_t)wid * DPAD + c0 + j] = 0; outl[(size_t)wid * DPAD + c0 + j] = 0; }
            else outf[(size_t)wid * DPAD + c0 + j] = 0.0f;
        }
        return;
    }
    bool act = (c0 + VEC <= D);
    float acc[VEC];
#pragma unroll
    for (int j = 0; j < VEC; ++j) acc[j] = 0.0f;
    float di = dinv[wid];
    float sw = di * di;
    if (act) {
        const float* hp = H + (size_t)wid * D + c0;
#pragma unroll
        for (int j = 0; j < VEC; ++j) acc[j] = sw * hp[j];
    }
    int e = offs[wid];
    int end = e + deg[wid];
    for (; e + 3 < end; e += 4) {
        uint2 q0 = epk[e], q1 = epk[e + 1], q2 = epk[e + 2], q3 = epk[e + 3];
        if (act) {
            const float* h0 = H + (size_t)q0.x * D + c0;
            const float* h1 = H + (size_t)q1.x * D + c0;
            const float* h2 = H + (size_t)q2.x * D + c0;
            const float* h3 = H + (size_t)q3.x * D + c0;
            float w0 = __uint_as_float(q0.y), w1 = __uint_as_float(q1.y);
            float w2 = __uint_as_float(q2.y), w3 = __uint_as_float(q3.y);
#pragma unroll
            for (int j = 0; j < VEC; ++j) acc[j] += w0 * h0[j];
#pragma unroll
            for (int j = 0; j < VEC; ++j) acc[j] += w1 * h1[j];
#pragma unroll
            for (int j = 0; j < VEC; ++j) acc[j] += w2 * h2[j];
#pragma unroll
            for (int j = 0; j < VEC; ++j) acc[j] += w3 * h3[j];
        }
    }
    for (; e < end; ++e) {
        uint2 q0 = epk[e];
        if (act) {
            const float* h0 = H + (size_t)q0.x * D + c0;
            float w0 = __uint_as_float(q0.y);
#pragma unroll
            for (int j = 0; j < VEC; ++j) acc[j] += w0 * h0[j];
        }
    }
#pragma unroll
    for (int j = 0; j < VEC; ++j) {
        float v = act ? acc[j] : 0.0f;
        if (BR && act) v = fmaxf(v + bias[c0 + j], 0.0f);
        if (SPLIT) {
            ushort hi = f2bf(v);
            ushort lo = f2bf(v - bf2f(hi));
            outh[(size_t)wid * DPAD + c0 + j] = hi;
            outl[(size_t)wid * DPAD + c0 + j] = lo;
        } else {
            outf[(size_t)wid * DPAD + c0 + j] = v;
        }
    }
}

// Layer-1 aggregation of x: gather only non-proto (group-2) sources via CSR2;
// proto sources contribute protoW[d][g] * nf_row(g). D=100, DPAD=128, split out.
__global__ void k_agg1(const float* __restrict__ x, const float* __restrict__ nf,
                       ushort* __restrict__ outh, ushort* __restrict__ outl,
                       const float* __restrict__ dinv, const int* __restrict__ offs2,
                       const int* __restrict__ deg2, const uint2* __restrict__ epk2,
                       const float* __restrict__ protoW, int NN, int NNpad) {
    int wid = (int)((blockIdx.x * blockDim.x + threadIdx.x) >> 6);
    int lane = threadIdx.x & 63;
    if (wid >= NNpad) return;
    constexpr int VEC = 2;
    constexpr int D = 100, DPAD = 128;
    int c0 = lane * VEC;
    if (wid >= NN) {
#pragma unroll
        for (int j = 0; j < VEC; ++j) {
            outh[(size_t)wid * DPAD + c0 + j] = 0;
            outl[(size_t)wid * DPAD + c0 + j] = 0;
        }
        return;
    }
    bool act = (c0 + VEC <= D);
    float acc[VEC];
#pragma unroll
    for (int j = 0; j < VEC; ++j) acc[j] = 0.0f;
    float di = dinv[wid];
    float sw = di * di;
    if (act) {
        const float* hp = x + (size_t)wid * D + c0;
#pragma unroll
        for (int j = 0; j < VEC; ++j) acc[j] = sw * hp[j];
    }
    int e = offs2[wid];
    int end = e + deg2[wid];
    for (; e + 3 < end; e += 4) {
        uint2 q0 = epk2[e], q1 = epk2[e + 1], q2 = epk2[e + 2], q3 = epk2[e + 3];
        if (act) {
            const float* h0 = x + (size_t)q0.x * D + c0;
            const float* h1 = x + (size_t)q1.x * D + c0;
            const float* h2 = x + (size_t)q2.x * D + c0;
            const float* h3 = x + (size_t)q3.x * D + c0;
            float w0 = __uint_as_float(q0.y), w1 = __uint_as_float(q1.y);
            float w2 = __uint_as_float(q2.y), w3 = __uint_as_float(q3.y);
#pragma unroll
            for (int j = 0; j < VEC; ++j) acc[j] += w0 * h0[j];
#pragma unroll
            for (int j = 0; j < VEC; ++j) acc[j] += w1 * h1[j];
#pragma unroll
            for (int j = 0; j < VEC; ++j) acc[j] += w2 * h2[j];
#pragma unroll
            for (int j = 0; j < VEC; ++j) acc[j] += w3 * h3[j];
        }
    }
    for (; e < end; ++e) {
        uint2 q0 = epk2[e];
        if (act) {
            const float* h0 = x + (size_t)q0.x * D + c0;
            float w0 = __uint_as_float(q0.y);
#pragma unroll
            for (int j = 0; j < VEC; ++j) acc[j] += w0 * h0[j];
        }
    }
    // prototype contributions: gid 0 -> nf row 0, gid 3 -> nf row 1, gid 1 -> nf row 2
    float pw0 = protoW[wid * 4 + 0];
    float pw1 = protoW[wid * 4 + 1];
    float pw3 = protoW[wid * 4 + 3];
    if (act) {
#pragma unroll
        for (int j = 0; j < VEC; ++j) {
            acc[j] += pw0 * nf[0 * 100 + c0 + j] + pw3 * nf[1 * 100 + c0 + j] + pw1 * nf[2 * 100 + c0 + j];
        }
    }
#pragma unroll
    for (int j = 0; j < VEC; ++j) {
        float v = act ? acc[j] : 0.0f;
        ushort hi = f2bf(v);
        ushort lo = f2bf(v - bf2f(hi));
        outh[(size_t)wid * DPAD + c0 + j] = hi;
        outl[(size_t)wid * DPAD + c0 + j] = lo;
    }
}

// ---------------- MFMA GEMM (pre-split bf16 hi/lo, 3-term), LDS-tiled ----------------

template <bool BR, int OUT>
__global__ __launch_bounds__(256) void k_gemm(
        const ushort* __restrict__ Ah, const ushort* __restrict__ Al,
        const ushort* __restrict__ Bh, const ushort* __restrict__ Bl,
        const float* __restrict__ bias,
        float* __restrict__ Cf, ushort* __restrict__ Ch, ushort* __restrict__ Cl,
        int Nc, int K, int tNb) {
    __shared__ union {
        ushort st[4][128 * 32];
        float epi[64 * 132];
    } sm;
    int bm = blockIdx.x / tNb, bn = blockIdx.x % tNb;
    int m0 = bm * 128, n0 = bn * 128;
    int wv = threadIdx.x >> 6, lane = threadIdx.x & 63;
    int l15 = lane & 15, quad = lane >> 4;
    const ushort* gT = (wv == 0) ? Ah + (size_t)m0 * K
                     : (wv == 1) ? Al + (size_t)m0 * K
                     : (wv == 2) ? Bh + (size_t)n0 * K
                     :             Bl + (size_t)n0 * K;
    ushort* sT = sm.st[wv];
    const ushort* gBase = gT + (size_t)(lane >> 2) * K + (lane & 3) * 8;
    int wm = (wv >> 1) * 64, wn = (wv & 1) * 64;
    const ushort* sAh_ = sm.st[0];
    const ushort* sAl_ = sm.st[1];
    const ushort* sBh_ = sm.st[2];
    const ushort* sBl_ = sm.st[3];
    f32x4 acc[4][4] = {};
    for (int k0 = 0; k0 < K; k0 += 32) {
#pragma unroll
        for (int i = 0; i < 8; ++i)
            gll(gBase + (size_t)(16 * i) * K + k0, sT + i * 512);
        __syncthreads();
        bf16x8 Afh[4], Afl[4], Bfh[4], Bfl[4];
#pragma unroll
        for (int i = 0; i < 4; ++i) {
            int ra = (wm + 16 * i + l15) * 32 + quad * 8;
            int rb = (wn + 16 * i + l15) * 32 + quad * 8;
            Afh[i] = *(const bf16x8*)(sAh_ + ra);
            Afl[i] = *(const bf16x8*)(sAl_ + ra);
            Bfh[i] = *(const bf16x8*)(sBh_ + rb);
            Bfl[i] = *(const bf16x8*)(sBl_ + rb);
        }
#pragma unroll
        for (int mi = 0; mi < 4; ++mi)
#pragma unroll
            for (int ni = 0; ni < 4; ++ni) {
                acc[mi][ni] = __builtin_amdgcn_mfma_f32_16x16x32_bf16(Afh[mi], Bfh[ni], acc[mi][ni], 0, 0, 0);
                acc[mi][ni] = __builtin_amdgcn_mfma_f32_16x16x32_bf16(Afh[mi], Bfl[ni], acc[mi][ni], 0, 0, 0);
                acc[mi][ni] = __builtin_amdgcn_mfma_f32_16x16x32_bf16(Afl[mi], Bfh[ni], acc[mi][ni], 0, 0, 0);
            }
        __syncthreads();
    }
    float bia[4] = {0.f, 0.f, 0.f, 0.f};
    if (BR) {
#pragma unroll
        for (int ni = 0; ni < 4; ++ni) {
            int col = n0 + wn + 16 * ni + l15;
            if (col < Nc) bia[ni] = bias[col];
        }
    }
    float* epi = sm.epi;
    int t = threadIdx.x;
    for (int half = 0; half < 2; ++half) {
        if ((wv >> 1) == half) {
#pragma unroll
            for (int mi = 0; mi < 4; ++mi)
#pragma unroll
                for (int r = 0; r < 4; ++r) {
                    int rl = mi * 16 + quad * 4 + r;
#pragma unroll
                    for (int ni = 0; ni < 4; ++ni) {
                        float v = acc[mi][ni][r];
                        if (BR) v = fmaxf(v + bia[ni], 0.0f);
                        epi[rl * 132 + wn + ni * 16 + l15] = v;
                    }
                }
        }
        __syncthreads();
#pragma unroll
        for (int j = 0; j < 16; ++j) {
            int e = (j * 256 + t) * 2;
            int rl = e >> 7, cl = e & 127;
            int grow = m0 + half * 64 + rl;
            int gcol = n0 + cl;
            float v0 = epi[rl * 132 + cl];
            float v1 = epi[rl * 132 + cl + 1];
            if (OUT == 0) {
                if (gcol < Nc) {
                    float2 w; w.x = v0; w.y = v1;
                    *(float2*)&Cf[(size_t)grow * Nc + gcol] = w;
                }
            } else {
                ushort h0 = f2bf(v0), h1 = f2bf(v1);
                ushort l0 = f2bf(v0 - bf2f(h0)), l1 = f2bf(v1 - bf2f(h1));
                *(uint*)&Ch[(size_t)grow * Nc + gcol] = (uint)h0 | ((uint)h1 << 16);
                *(uint*)&Cl[(size_t)grow * Nc + gcol] = (uint)l0 | ((uint)l1 << 16);
            }
        }
        __syncthreads();
    }
}

// ---------------- weight transpose + split ----------------

__global__ void k_tr2(const float* __restrict__ W, ushort* __restrict__ WTh, ushort* __restrict__ WTl,
                      int K, int Nc, int KP, int NP) {
    int idx = blockIdx.x * blockDim.x + threadIdx.x;
    if (idx >= NP * KP) return;
    int n = idx / KP, k = idx % KP;
    float w = (n < Nc && k < K) ? W[(size_t)k * Nc + n] : 0.0f;
    ushort hi = f2bf(w);
    ushort lo = f2bf(w - bf2f(hi));
    WTh[idx] = hi;
    WTl[idx] = lo;
}

// ---------------- group reduce / final ----------------

__global__ void k_reduce(const float* __restrict__ H4, const int* __restrict__ gid,
                         float* __restrict__ gsum, int NN) {
    int d = threadIdx.x;
    if (d >= 200) return;
    int n0 = blockIdx.x * 256;
    int n1 = min(n0 + 256, NN);
    float r0 = 0.f, r1 = 0.f, r2 = 0.f, r3 = 0.f;
    for (int n = n0; n < n1; ++n) {
        int g = gid[n];
        float v = H4[(size_t)n * 200 + d];
        r0 += (g == 0) ? v : 0.f;
        r1 += (g == 1) ? v : 0.f;
        r2 += (g == 2) ? v : 0.f;
        r3 += (g == 3) ? v : 0.f;
    }
    atomicAdd(&gsum[0 * 200 + d], r0);
    atomicAdd(&gsum[1 * 200 + d], r1);
    atomicAdd(&gsum[2 * 200 + d], r2);
    atomicAdd(&gsum[3 * 200 + d], r3);
}

__global__ void k_final(const float* __restrict__ gsum, const int* __restrict__ gcnt,
                        float* __restrict__ out) {
    int j = blockIdx.x * blockDim.x + threadIdx.x;
    if (j >= 800) return;
    int g = j / 200;
    int c = gcnt[g];
    out[j] = (c > 0) ? gsum[j] / (float)c : 0.0f;
}

// ---------------- launch ----------------

extern "C" void kernel_launch(void* const* d_in, const int* in_sizes, int n_in,
                              void* d_out, int out_size, void* d_ws, size_t ws_size,
                              hipStream_t stream) {
    const float* x  = (const float*)d_in[0];
    const float* nf = (const float*)d_in[1];
    const int* ei   = (const int*)d_in[2];
    const float* W1 = (const float*)d_in[3];
    const float* b1 = (const float*)d_in[4];
    const float* W2 = (const float*)d_in[5];
    const float* b2 = (const float*)d_in[6];
    const float* W3 = (const float*)d_in[7];
    const float* b3 = (const float*)d_in[8];
    const float* W4 = (const float*)d_in[9];
    const float* b4 = (const float*)d_in[10];
    float* out = (float*)d_out;

    const int NN = in_sizes[0] / 100;  // 50000
    const int E  = in_sizes[2] / 2;    // 800000
    const int MPAD = ((NN + 127) / 128) * 128;  // 50048
    const int* src = ei;
    const int* dst = ei + E;

    char* p = (char*)d_ws;
    auto alloc = [&](size_t bytes) -> char* {
        char* r = p;
        p += (bytes + 255) & ~(size_t)255;
        return r;
    };
    char* zz = p;
    int*   deg   = (int*)alloc((size_t)NN * 4);
    int*   cur   = (int*)alloc((size_t)NN * 4);
    int*   deg2  = (int*)alloc((size_t)NN * 4);
    int*   cur2  = (int*)alloc((size_t)NN * 4);
    float* protoW = (float*)alloc((size_t)NN * 4 * 4);
    int*   gcnt  = (int*)alloc(256);
    float* gsum  = (float*)alloc(800 * 4);
    size_t zz_bytes = (size_t)(p - zz);
    float* dinv = (float*)alloc((size_t)NN * 4);
    int*   offs = (int*)alloc((size_t)NN * 4);
    int*   offs2 = (int*)alloc((size_t)NN * 4);
    int*   gid  = (int*)alloc((size_t)NN * 4);
    uint2* epk  = (uint2*)alloc((size_t)E * 8);
    uint2* epk2 = (uint2*)alloc((size_t)E * 8);
    ushort* WT1h = (ushort*)alloc((size_t)512 * 128 * 2);
    ushort* WT1l = (ushort*)alloc((size_t)512 * 128 * 2);
    ushort* WT2h = (ushort*)alloc((size_t)256 * 512 * 2);
    ushort* WT2l = (ushort*)alloc((size_t)256 * 512 * 2);
    ushort* WT3h = (ushort*)alloc((size_t)128 * 256 * 2);
    ushort* WT3l = (ushort*)alloc((size_t)128 * 256 * 2);
    ushort* WT4h = (ushort*)alloc((size_t)256 * 128 * 2);
    ushort* WT4l = (ushort*)alloc((size_t)256 * 128 * 2);
    // Region A: H1 split; later P4 split
    ushort* H1h = (ushort*)alloc((size_t)MPAD * 512 * 2);
    ushort* H1l = (ushort*)alloc((size_t)MPAD * 512 * 2);
    ushort* P4h = H1h;
    ushort* P4l = H1h + (size_t)MPAD * 128;
    // Region B: T2 f32; later H3 f32
    float* T2 = (float*)alloc((size_t)MPAD * 256 * 4);
    float* H3 = T2;
    // Region C: P1 split; later H2 split; later H4 f32
    char* regC = alloc((size_t)MPAD * 256 * 2 * 2);
    ushort* P1h = (ushort*)regC;
    ushort* P1l = (ushort*)(regC + (size_t)MPAD * 128 * 2);
    ushort* H2h = (ushort*)regC;
    ushort* H2l = (ushort*)(regC + (size_t)MPAD * 256 * 2);
    float*  H4  = (float*)regC;
    // Region D: T3 f32
    float* T3 = (float*)alloc((size_t)MPAD * 128 * 4);

    hipMemsetAsync(zz, 0, zz_bytes, stream);

    k_group<<<(NN + 255) / 256, 256, 0, stream>>>((const uint4*)x, (const uint4*)nf, NN, gid, gcnt);
    k_deg<<<(E + 255) / 256, 256, 0, stream>>>(src, dst, gid, E, deg, deg2);
    k_dinv<<<(NN + 255) / 256, 256, 0, stream>>>(deg, dinv, NN);
    k_scan<<<1, 1024, 0, stream>>>(deg, offs, NN);
    k_scan<<<1, 1024, 0, stream>>>(deg2, offs2, NN);
    k_fill<<<(E + 255) / 256, 256, 0, stream>>>(src, dst, E, dinv, gid, offs, cur, epk, offs2, cur2, epk2, protoW);

    k_tr2<<<(512 * 128 + 255) / 256, 256, 0, stream>>>(W1, WT1h, WT1l, 100, 512, 128, 512);
    k_tr2<<<(256 * 512 + 255) / 256, 256, 0, stream>>>(W2, WT2h, WT2l, 512, 256, 512, 256);
    k_tr2<<<(128 * 256 + 255) / 256, 256, 0, stream>>>(W3, WT3h, WT3l, 256, 128, 256, 128);
    k_tr2<<<(256 * 128 + 255) / 256, 256, 0, stream>>>(W4, WT4h, WT4l, 128, 200, 128, 256);

    int aggBlocks = MPAD / 4;  // one wave per node incl. pad rows
    int mB = MPAD / 128;

    // P1 = agg(x) via reduced CSR + proto weights -> split [MPAD,128]
    k_agg1<<<aggBlocks, 256, 0, stream>>>(x, nf, P1h, P1l, dinv, offs2, deg2, epk2, protoW, NN, MPAD);
    // H1 = relu(P1 @ W1 + b1) -> split [MPAD,512]
    k_gemm<true, 1><<<mB * 4, 256, 0, stream>>>(P1h, P1l, WT1h, WT1l, b1, nullptr, H1h, H1l, 512, 128, 4);
    // T2 = H1 @ W2 -> f32 [MPAD,256]
    k_gemm<false, 0><<<mB * 2, 256, 0, stream>>>(H1h, H1l, WT2h, WT2l, nullptr, T2, nullptr, nullptr, 256, 512, 2);
    // H2 = relu(agg(T2) + b2) -> split [MPAD,256]
    k_agg<256, 256, true, true><<<aggBlocks, 256, 0, stream>>>(T2, nullptr, H2h, H2l, dinv, offs, deg, epk, b2, NN, MPAD);
    // T3 = H2 @ W3 -> f32 [MPAD,128]
    k_gemm<false, 0><<<mB * 1, 256, 0, stream>>>(H2h, H2l, WT3h, WT3l, nullptr, T3, nullptr, nullptr, 128, 256, 1);
    // H3 = relu(agg(T3) + b3) -> f32 [MPAD,128]  (region B; T2 dead)
    k_agg<128, 128, true, false><<<aggBlocks, 256, 0, stream>>>(T3, H3, nullptr, nullptr, dinv, offs, deg, epk, b3, NN, MPAD);
    // P4 = agg(H3) -> split [MPAD,128]  (region A; H1 dead)
    k_agg<128, 128, false, true><<<aggBlocks, 256, 0, stream>>>(H3, nullptr, P4h, P4l, dinv, offs, deg, epk, nullptr, NN, MPAD);
    // H4 = relu(P4 @ W4 + b4) -> f32 [MPAD,200]  (region C; H2 dead)
    k_gemm<true, 0><<<mB * 2, 256, 0, stream>>>(P4h, P4l, WT4h, WT4l, b4, H4, nullptr, nullptr, 200, 128, 2);

    k_reduce<<<(NN + 255) / 256, 256, 0, stream>>>(H4, gid, gsum, NN);
    k_final<<<4, 256, 0, stream>>>(gsum, gcnt, out);
}

// Round 6
// 856.936 us; speedup vs baseline: 1.0144x; 1.0144x over previous
//
#include <hip/hip_runtime.h>
#include <stdint.h>

typedef __attribute__((ext_vector_type(8))) short bf16x8;
typedef __attribute__((ext_vector_type(4))) float f32x4;

__device__ __forceinline__ float bf2f(ushort h) {
    union { uint u; float f; } v; v.u = ((uint)h) << 16; return v.f;
}
__device__ __forceinline__ ushort f2bf(float f) {
    union { float f; uint u; } v; v.f = f;
    uint u = v.u;
    return (ushort)((u + 0x7fffu + ((u >> 16) & 1u)) >> 16);
}

// async global->LDS, 16B per lane; LDS dest = wave-uniform base + lane*16
__device__ __forceinline__ void gll(const ushort* g, ushort* l) {
    __builtin_amdgcn_global_load_lds(
        (const __attribute__((address_space(1))) void*)g,
        (__attribute__((address_space(3))) void*)l, 16, 0, 0);
}

// ---------------- graph prep ----------------

__global__ void k_group(const uint4* __restrict__ x4, const uint4* __restrict__ nf4, int NN,
                        int* __restrict__ gid, int* __restrict__ gcnt) {
    __shared__ int cnt[4];
    if (threadIdx.x < 4) cnt[threadIdx.x] = 0;
    __syncthreads();
    int i = blockIdx.x * blockDim.x + threadIdx.x;
    if (i < NN) {
        const uint4* xr = x4 + (size_t)i * 25;  // 100 floats = 25 uint4
        bool e0 = true, e1 = true, e2 = true;
#pragma unroll 5
        for (int d = 0; d < 25; ++d) {
            uint4 v = xr[d];
            uint4 a = nf4[d], b = nf4[25 + d], c = nf4[50 + d];
            e0 &= (v.x == a.x) & (v.y == a.y) & (v.z == a.z) & (v.w == a.w);
            e1 &= (v.x == b.x) & (v.y == b.y) & (v.z == b.z) & (v.w == b.w);
            e2 &= (v.x == c.x) & (v.y == c.y) & (v.z == c.z) & (v.w == c.w);
        }
        int g = e0 ? 0 : (e1 ? 3 : (e2 ? 1 : 2));
        gid[i] = g;
        atomicAdd(&cnt[g], 1);
    }
    __syncthreads();
    if (threadIdx.x < 4 && cnt[threadIdx.x]) atomicAdd(&gcnt[threadIdx.x], cnt[threadIdx.x]);
}

__global__ void k_deg(const int* __restrict__ dst, int E, int* __restrict__ deg) {
    int e = blockIdx.x * blockDim.x + threadIdx.x;
    if (e < E) atomicAdd(&deg[dst[e]], 1);
}

__global__ void k_dinv(const int* __restrict__ deg, float* __restrict__ dinv, int NN) {
    int i = blockIdx.x * blockDim.x + threadIdx.x;
    if (i < NN) dinv[i] = 1.0f / sqrtf((float)(deg[i] + 1));  // +1 self loop
}

__global__ void k_scan(const int* __restrict__ deg, int* __restrict__ offs, int NN) {
    __shared__ int lds[1024];
    int t = threadIdx.x;
    int chunk = (NN + 1023) / 1024;
    int b0 = t * chunk;
    int b1 = min(b0 + chunk, NN);
    int s = 0;
    for (int i = b0; i < b1; ++i) s += deg[i];
    lds[t] = s;
    __syncthreads();
    for (int d = 1; d < 1024; d <<= 1) {
        int v = (t >= d) ? lds[t - d] : 0;
        __syncthreads();
        lds[t] += v;
        __syncthreads();
    }
    int excl = (t == 0) ? 0 : lds[t - 1];
    for (int i = b0; i < b1; ++i) { offs[i] = excl; excl += deg[i]; }
}

__global__ void k_fill(const int* __restrict__ src, const int* __restrict__ dst, int E,
                       const float* __restrict__ dinv, const int* __restrict__ offs,
                       int* __restrict__ cur, uint2* __restrict__ epk) {
    int e = blockIdx.x * blockDim.x + threadIdx.x;
    if (e >= E) return;
    int s = src[e], d = dst[e];
    int p = offs[d] + atomicAdd(&cur[d], 1);
    epk[p] = make_uint2((uint)s, __float_as_uint(dinv[s] * dinv[d]));
}

// ---------------- aggregation (gather, wave per node) ----------------

template <int D, int DPAD, bool BR, bool SPLIT>
__global__ void k_agg(const float* __restrict__ H,
                      float* __restrict__ outf, ushort* __restrict__ outh, ushort* __restrict__ outl,
                      const float* __restrict__ dinv, const int* __restrict__ offs,
                      const int* __restrict__ deg, const uint2* __restrict__ epk,
                      const float* __restrict__ bias,
                      int NN, int NNpad) {
    int wid = (int)((blockIdx.x * blockDim.x + threadIdx.x) >> 6);
    int lane = threadIdx.x & 63;
    if (wid >= NNpad) return;
    constexpr int VEC = DPAD / 64;
    int c0 = lane * VEC;
    if (wid >= NN) {  // zero pad rows so GEMM A-tiles are clean
#pragma unroll
        for (int j = 0; j < VEC; ++j) {
            if (SPLIT) { outh[(size_t)wid * DPAD + c0 + j] = 0; outl[(size_t)wid * DPAD + c0 + j] = 0; }
            else outf[(size_t)wid * DPAD + c0 + j] = 0.0f;
        }
        return;
    }
    bool act = (c0 + VEC <= D);
    float acc[VEC];
#pragma unroll
    for (int j = 0; j < VEC; ++j) acc[j] = 0.0f;
    float di = dinv[wid];
    float sw = di * di;
    if (act) {
        const float* hp = H + (size_t)wid * D + c0;
#pragma unroll
        for (int j = 0; j < VEC; ++j) acc[j] = sw * hp[j];
    }
    int e = offs[wid];
    int end = e + deg[wid];
    for (; e + 1 < end; e += 2) {
        uint2 q0 = epk[e], q1 = epk[e + 1];
        if (act) {
            const float* h0 = H + (size_t)q0.x * D + c0;
            const float* h1 = H + (size_t)q1.x * D + c0;
            float w0 = __uint_as_float(q0.y), w1 = __uint_as_float(q1.y);
#pragma unroll
            for (int j = 0; j < VEC; ++j) acc[j] += w0 * h0[j];
#pragma unroll
            for (int j = 0; j < VEC; ++j) acc[j] += w1 * h1[j];
        }
    }
    if (e < end) {
        uint2 q0 = epk[e];
        if (act) {
            const float* h0 = H + (size_t)q0.x * D + c0;
            float w0 = __uint_as_float(q0.y);
#pragma unroll
            for (int j = 0; j < VEC; ++j) acc[j] += w0 * h0[j];
        }
    }
#pragma unroll
    for (int j = 0; j < VEC; ++j) {
        float v = act ? acc[j] : 0.0f;
        if (BR && act) v = fmaxf(v + bias[c0 + j], 0.0f);
        if (SPLIT) {
            ushort hi = f2bf(v);
            ushort lo = f2bf(v - bf2f(hi));
            outh[(size_t)wid * DPAD + c0 + j] = hi;
            outl[(size_t)wid * DPAD + c0 + j] = lo;
        } else {
            outf[(size_t)wid * DPAD + c0 + j] = v;
        }
    }
}

// ---------------- fused GEMM1+GEMM2 ----------------
// Per block: 32 rows. Phase 1: H1strip = relu(P1[32,128] @ W1T[512,128]^T + b1),
// split hi/lo into LDS (fragment-major: [col/8][row][col%8], conflict-free b128).
// Phase 2: T2[32,256] = H1strip @ W2T[256,512]^T, LDS-buffered coalesced store.

__global__ __launch_bounds__(256) void k_fused12(
        const ushort* __restrict__ Ah, const ushort* __restrict__ Al,
        const ushort* __restrict__ B1h, const ushort* __restrict__ B1l,
        const ushort* __restrict__ B2h, const ushort* __restrict__ B2l,
        const float* __restrict__ b1, float* __restrict__ T2) {
    __shared__ ushort sH[2][64 * 256];  // 2 planes x 32KB (frag-major: frag*256 + row*8 + e)
    int r0 = blockIdx.x * 32;
    int wv = threadIdx.x >> 6, lane = threadIdx.x & 63;
    int l15 = lane & 15, quad = lane >> 4;
    // ---- phase 1: 32 x 512, wave wv covers cols [wv*128, wv*128+128) ----
    int nb = wv * 128;
    f32x4 acc1[2][8] = {};
#pragma unroll
    for (int ks = 0; ks < 4; ++ks) {
        int k = ks * 32 + quad * 8;
        bf16x8 a00 = *(const bf16x8*)(Ah + (size_t)(r0 + l15) * 128 + k);
        bf16x8 a01 = *(const bf16x8*)(Al + (size_t)(r0 + l15) * 128 + k);
        bf16x8 a10 = *(const bf16x8*)(Ah + (size_t)(r0 + 16 + l15) * 128 + k);
        bf16x8 a11 = *(const bf16x8*)(Al + (size_t)(r0 + 16 + l15) * 128 + k);
#pragma unroll
        for (int ni = 0; ni < 8; ++ni) {
            bf16x8 bh = *(const bf16x8*)(B1h + (size_t)(nb + ni * 16 + l15) * 128 + k);
            bf16x8 bl = *(const bf16x8*)(B1l + (size_t)(nb + ni * 16 + l15) * 128 + k);
            acc1[0][ni] = __builtin_amdgcn_mfma_f32_16x16x32_bf16(a00, bh, acc1[0][ni], 0, 0, 0);
            acc1[0][ni] = __builtin_amdgcn_mfma_f32_16x16x32_bf16(a00, bl, acc1[0][ni], 0, 0, 0);
            acc1[0][ni] = __builtin_amdgcn_mfma_f32_16x16x32_bf16(a01, bh, acc1[0][ni], 0, 0, 0);
            acc1[1][ni] = __builtin_amdgcn_mfma_f32_16x16x32_bf16(a10, bh, acc1[1][ni], 0, 0, 0);
            acc1[1][ni] = __builtin_amdgcn_mfma_f32_16x16x32_bf16(a10, bl, acc1[1][ni], 0, 0, 0);
            acc1[1][ni] = __builtin_amdgcn_mfma_f32_16x16x32_bf16(a11, bh, acc1[1][ni], 0, 0, 0);
        }
    }
#pragma unroll
    for (int ni = 0; ni < 8; ++ni) {
        int col = nb + ni * 16 + l15;
        float bv = b1[col];
        int fo = (col >> 3) * 256 + (col & 7);
#pragma unroll
        for (int mi = 0; mi < 2; ++mi)
#pragma unroll
            for (int r = 0; r < 4; ++r) {
                int row = mi * 16 + quad * 4 + r;
                float v = fmaxf(acc1[mi][ni][r] + bv, 0.0f);
                ushort hi = f2bf(v);
                ushort lo = f2bf(v - bf2f(hi));
                sH[0][fo + row * 8] = hi;
                sH[1][fo + row * 8] = lo;
            }
    }
    __syncthreads();
    // ---- phase 2: T2[32,256], wave wv covers cols [wv*64, wv*64+64) ----
    int n2 = wv * 64;
    f32x4 acc2[2][4] = {};
#pragma unroll
    for (int ks = 0; ks < 16; ++ks) {
        int k = ks * 32 + quad * 8;
        int fo = (k >> 3) * 256;
        bf16x8 a00 = *(const bf16x8*)(&sH[0][fo + l15 * 8]);
        bf16x8 a01 = *(const bf16x8*)(&sH[1][fo + l15 * 8]);
        bf16x8 a10 = *(const bf16x8*)(&sH[0][fo + (16 + l15) * 8]);
        bf16x8 a11 = *(const bf16x8*)(&sH[1][fo + (16 + l15) * 8]);
#pragma unroll
        for (int ni = 0; ni < 4; ++ni) {
            bf16x8 bh = *(const bf16x8*)(B2h + (size_t)(n2 + ni * 16 + l15) * 512 + k);
            bf16x8 bl = *(const bf16x8*)(B2l + (size_t)(n2 + ni * 16 + l15) * 512 + k);
            acc2[0][ni] = __builtin_amdgcn_mfma_f32_16x16x32_bf16(a00, bh, acc2[0][ni], 0, 0, 0);
            acc2[0][ni] = __builtin_amdgcn_mfma_f32_16x16x32_bf16(a00, bl, acc2[0][ni], 0, 0, 0);
            acc2[0][ni] = __builtin_amdgcn_mfma_f32_16x16x32_bf16(a01, bh, acc2[0][ni], 0, 0, 0);
            acc2[1][ni] = __builtin_amdgcn_mfma_f32_16x16x32_bf16(a10, bh, acc2[1][ni], 0, 0, 0);
            acc2[1][ni] = __builtin_amdgcn_mfma_f32_16x16x32_bf16(a10, bl, acc2[1][ni], 0, 0, 0);
            acc2[1][ni] = __builtin_amdgcn_mfma_f32_16x16x32_bf16(a11, bh, acc2[1][ni], 0, 0, 0);
        }
    }
    __syncthreads();
    float* epi = (float*)sH;  // 32 x 260 padded
#pragma unroll
    for (int mi = 0; mi < 2; ++mi)
#pragma unroll
        for (int r = 0; r < 4; ++r) {
            int row = mi * 16 + quad * 4 + r;
#pragma unroll
            for (int ni = 0; ni < 4; ++ni)
                epi[row * 260 + n2 + ni * 16 + l15] = acc2[mi][ni][r];
        }
    __syncthreads();
    int t = threadIdx.x;
#pragma unroll
    for (int j = 0; j < 8; ++j) {
        int idx = (j * 256 + t) * 4;
        int row = idx >> 8, col = idx & 255;
        float4 v;
        v.x = epi[row * 260 + col];
        v.y = epi[row * 260 + col + 1];
        v.z = epi[row * 260 + col + 2];
        v.w = epi[row * 260 + col + 3];
        *(float4*)&T2[(size_t)(r0 + row) * 256 + col] = v;
    }
}

// ---------------- MFMA GEMM (pre-split bf16 hi/lo, 3-term), LDS-tiled ----------------

template <bool BR, int OUT>
__global__ __launch_bounds__(256) void k_gemm(
        const ushort* __restrict__ Ah, const ushort* __restrict__ Al,
        const ushort* __restrict__ Bh, const ushort* __restrict__ Bl,
        const float* __restrict__ bias,
        float* __restrict__ Cf, ushort* __restrict__ Ch, ushort* __restrict__ Cl,
        int Nc, int K, int tNb) {
    __shared__ union {
        ushort st[4][128 * 32];
        float epi[64 * 132];
    } sm;
    int bm = blockIdx.x / tNb, bn = blockIdx.x % tNb;
    int m0 = bm * 128, n0 = bn * 128;
    int wv = threadIdx.x >> 6, lane = threadIdx.x & 63;
    int l15 = lane & 15, quad = lane >> 4;
    const ushort* gT = (wv == 0) ? Ah + (size_t)m0 * K
                     : (wv == 1) ? Al + (size_t)m0 * K
                     : (wv == 2) ? Bh + (size_t)n0 * K
                     :             Bl + (size_t)n0 * K;
    ushort* sT = sm.st[wv];
    const ushort* gBase = gT + (size_t)(lane >> 2) * K + (lane & 3) * 8;
    int wm = (wv >> 1) * 64, wn = (wv & 1) * 64;
    const ushort* sAh_ = sm.st[0];
    const ushort* sAl_ = sm.st[1];
    const ushort* sBh_ = sm.st[2];
    const ushort* sBl_ = sm.st[3];
    f32x4 acc[4][4] = {};
    for (int k0 = 0; k0 < K; k0 += 32) {
#pragma unroll
        for (int i = 0; i < 8; ++i)
            gll(gBase + (size_t)(16 * i) * K + k0, sT + i * 512);
        __syncthreads();
        bf16x8 Afh[4], Afl[4], Bfh[4], Bfl[4];
#pragma unroll
        for (int i = 0; i < 4; ++i) {
            int ra = (wm + 16 * i + l15) * 32 + quad * 8;
            int rb = (wn + 16 * i + l15) * 32 + quad * 8;
            Afh[i] = *(const bf16x8*)(sAh_ + ra);
            Afl[i] = *(const bf16x8*)(sAl_ + ra);
            Bfh[i] = *(const bf16x8*)(sBh_ + rb);
            Bfl[i] = *(const bf16x8*)(sBl_ + rb);
        }
#pragma unroll
        for (int mi = 0; mi < 4; ++mi)
#pragma unroll
            for (int ni = 0; ni < 4; ++ni) {
                acc[mi][ni] = __builtin_amdgcn_mfma_f32_16x16x32_bf16(Afh[mi], Bfh[ni], acc[mi][ni], 0, 0, 0);
                acc[mi][ni] = __builtin_amdgcn_mfma_f32_16x16x32_bf16(Afh[mi], Bfl[ni], acc[mi][ni], 0, 0, 0);
                acc[mi][ni] = __builtin_amdgcn_mfma_f32_16x16x32_bf16(Afl[mi], Bfh[ni], acc[mi][ni], 0, 0, 0);
            }
        __syncthreads();
    }
    float bia[4] = {0.f, 0.f, 0.f, 0.f};
    if (BR) {
#pragma unroll
        for (int ni = 0; ni < 4; ++ni) {
            int col = n0 + wn + 16 * ni + l15;
            if (col < Nc) bia[ni] = bias[col];
        }
    }
    float* epi = sm.epi;
    int t = threadIdx.x;
    for (int half = 0; half < 2; ++half) {
        if ((wv >> 1) == half) {
#pragma unroll
            for (int mi = 0; mi < 4; ++mi)
#pragma unroll
                for (int r = 0; r < 4; ++r) {
                    int rl = mi * 16 + quad * 4 + r;
#pragma unroll
                    for (int ni = 0; ni < 4; ++ni) {
                        float v = acc[mi][ni][r];
                        if (BR) v = fmaxf(v + bia[ni], 0.0f);
                        epi[rl * 132 + wn + ni * 16 + l15] = v;
                    }
                }
        }
        __syncthreads();
#pragma unroll
        for (int j = 0; j < 16; ++j) {
            int e = (j * 256 + t) * 2;
            int rl = e >> 7, cl = e & 127;
            int grow = m0 + half * 64 + rl;
            int gcol = n0 + cl;
            float v0 = epi[rl * 132 + cl];
            float v1 = epi[rl * 132 + cl + 1];
            if (OUT == 0) {
                if (gcol < Nc) {
                    float2 w; w.x = v0; w.y = v1;
                    *(float2*)&Cf[(size_t)grow * Nc + gcol] = w;
                }
            } else {
                ushort h0 = f2bf(v0), h1 = f2bf(v1);
                ushort l0 = f2bf(v0 - bf2f(h0)), l1 = f2bf(v1 - bf2f(h1));
                *(uint*)&Ch[(size_t)grow * Nc + gcol] = (uint)h0 | ((uint)h1 << 16);
                *(uint*)&Cl[(size_t)grow * Nc + gcol] = (uint)l0 | ((uint)l1 << 16);
            }
        }
        __syncthreads();
    }
}

// ---------------- weight transpose + split ----------------

__global__ void k_tr2(const float* __restrict__ W, ushort* __restrict__ WTh, ushort* __restrict__ WTl,
                      int K, int Nc, int KP, int NP) {
    int idx = blockIdx.x * blockDim.x + threadIdx.x;
    if (idx >= NP * KP) return;
    int n = idx / KP, k = idx % KP;
    float w = (n < Nc && k < K) ? W[(size_t)k * Nc + n] : 0.0f;
    ushort hi = f2bf(w);
    ushort lo = f2bf(w - bf2f(hi));
    WTh[idx] = hi;
    WTl[idx] = lo;
}

// ---------------- group reduce / final ----------------

__global__ void k_reduce(const float* __restrict__ H4, const int* __restrict__ gid,
                         float* __restrict__ gsum, int NN) {
    int d = threadIdx.x;
    if (d >= 200) return;
    int n0 = blockIdx.x * 256;
    int n1 = min(n0 + 256, NN);
    float r0 = 0.f, r1 = 0.f, r2 = 0.f, r3 = 0.f;
    for (int n = n0; n < n1; ++n) {
        int g = gid[n];
        float v = H4[(size_t)n * 200 + d];
        r0 += (g == 0) ? v : 0.f;
        r1 += (g == 1) ? v : 0.f;
        r2 += (g == 2) ? v : 0.f;
        r3 += (g == 3) ? v : 0.f;
    }
    atomicAdd(&gsum[0 * 200 + d], r0);
    atomicAdd(&gsum[1 * 200 + d], r1);
    atomicAdd(&gsum[2 * 200 + d], r2);
    atomicAdd(&gsum[3 * 200 + d], r3);
}

__global__ void k_final(const float* __restrict__ gsum, const int* __restrict__ gcnt,
                        float* __restrict__ out) {
    int j = blockIdx.x * blockDim.x + threadIdx.x;
    if (j >= 800) return;
    int g = j / 200;
    int c = gcnt[g];
    out[j] = (c > 0) ? gsum[j] / (float)c : 0.0f;
}

// ---------------- launch ----------------

extern "C" void kernel_launch(void* const* d_in, const int* in_sizes, int n_in,
                              void* d_out, int out_size, void* d_ws, size_t ws_size,
                              hipStream_t stream) {
    const float* x  = (const float*)d_in[0];
    const float* nf = (const float*)d_in[1];
    const int* ei   = (const int*)d_in[2];
    const float* W1 = (const float*)d_in[3];
    const float* b1 = (const float*)d_in[4];
    const float* W2 = (const float*)d_in[5];
    const float* b2 = (const float*)d_in[6];
    const float* W3 = (const float*)d_in[7];
    const float* b3 = (const float*)d_in[8];
    const float* W4 = (const float*)d_in[9];
    const float* b4 = (const float*)d_in[10];
    float* out = (float*)d_out;

    const int NN = in_sizes[0] / 100;  // 50000
    const int E  = in_sizes[2] / 2;    // 800000
    const int MPAD = ((NN + 127) / 128) * 128;  // 50048
    const int* src = ei;
    const int* dst = ei + E;

    char* p = (char*)d_ws;
    auto alloc = [&](size_t bytes) -> char* {
        char* r = p;
        p += (bytes + 255) & ~(size_t)255;
        return r;
    };
    char* zz = p;
    int*   deg  = (int*)alloc((size_t)NN * 4);
    int*   cur  = (int*)alloc((size_t)NN * 4);
    int*   gcnt = (int*)alloc(256);
    float* gsum = (float*)alloc(800 * 4);
    size_t zz_bytes = (size_t)(p - zz);
    float* dinv = (float*)alloc((size_t)NN * 4);
    int*   offs = (int*)alloc((size_t)NN * 4);
    int*   gid  = (int*)alloc((size_t)NN * 4);
    uint2* epk  = (uint2*)alloc((size_t)E * 8);
    ushort* WT1h = (ushort*)alloc((size_t)512 * 128 * 2);
    ushort* WT1l = (ushort*)alloc((size_t)512 * 128 * 2);
    ushort* WT2h = (ushort*)alloc((size_t)256 * 512 * 2);
    ushort* WT2l = (ushort*)alloc((size_t)256 * 512 * 2);
    ushort* WT3h = (ushort*)alloc((size_t)128 * 256 * 2);
    ushort* WT3l = (ushort*)alloc((size_t)128 * 256 * 2);
    ushort* WT4h = (ushort*)alloc((size_t)256 * 128 * 2);
    ushort* WT4l = (ushort*)alloc((size_t)256 * 128 * 2);
    ushort* P1h = (ushort*)alloc((size_t)MPAD * 128 * 2);
    ushort* P1l = (ushort*)alloc((size_t)MPAD * 128 * 2);
    float*  T2  = (float*)alloc((size_t)MPAD * 256 * 4);
    ushort* H2h = (ushort*)alloc((size_t)MPAD * 256 * 2);
    ushort* H2l = (ushort*)alloc((size_t)MPAD * 256 * 2);
    float*  T3  = (float*)alloc((size_t)MPAD * 128 * 4);
    float*  H3  = (float*)alloc((size_t)MPAD * 128 * 4);
    ushort* P4h = (ushort*)alloc((size_t)MPAD * 128 * 2);
    ushort* P4l = (ushort*)alloc((size_t)MPAD * 128 * 2);
    float*  H4  = (float*)alloc((size_t)MPAD * 200 * 4);

    hipMemsetAsync(zz, 0, zz_bytes, stream);

    k_group<<<(NN + 255) / 256, 256, 0, stream>>>((const uint4*)x, (const uint4*)nf, NN, gid, gcnt);
    k_deg<<<(E + 255) / 256, 256, 0, stream>>>(dst, E, deg);
    k_dinv<<<(NN + 255) / 256, 256, 0, stream>>>(deg, dinv, NN);
    k_scan<<<1, 1024, 0, stream>>>(deg, offs, NN);
    k_fill<<<(E + 255) / 256, 256, 0, stream>>>(src, dst, E, dinv, offs, cur, epk);

    k_tr2<<<(512 * 128 + 255) / 256, 256, 0, stream>>>(W1, WT1h, WT1l, 100, 512, 128, 512);
    k_tr2<<<(256 * 512 + 255) / 256, 256, 0, stream>>>(W2, WT2h, WT2l, 512, 256, 512, 256);
    k_tr2<<<(128 * 256 + 255) / 256, 256, 0, stream>>>(W3, WT3h, WT3l, 256, 128, 256, 128);
    k_tr2<<<(256 * 128 + 255) / 256, 256, 0, stream>>>(W4, WT4h, WT4l, 128, 200, 128, 256);

    int aggBlocks = MPAD / 4;  // one wave per node incl. pad rows
    int mB = MPAD / 128;

    // P1 = agg(x) -> split [MPAD,128]
    k_agg<100, 128, false, true><<<aggBlocks, 256, 0, stream>>>(x, nullptr, P1h, P1l, dinv, offs, deg, epk, nullptr, NN, MPAD);
    // T2 = relu(P1@W1+b1) @ W2 -> f32 [MPAD,256]  (H1 never materialized)
    k_fused12<<<MPAD / 32, 256, 0, stream>>>(P1h, P1l, WT1h, WT1l, WT2h, WT2l, b1, T2);
    // H2 = relu(agg(T2) + b2) -> split [MPAD,256]
    k_agg<256, 256, true, true><<<aggBlocks, 256, 0, stream>>>(T2, nullptr, H2h, H2l, dinv, offs, deg, epk, b2, NN, MPAD);
    // T3 = H2 @ W3 -> f32 [MPAD,128]
    k_gemm<false, 0><<<mB * 1, 256, 0, stream>>>(H2h, H2l, WT3h, WT3l, nullptr, T3, nullptr, nullptr, 128, 256, 1);
    // H3 = relu(agg(T3) + b3) -> f32 [MPAD,128]
    k_agg<128, 128, true, false><<<aggBlocks, 256, 0, stream>>>(T3, H3, nullptr, nullptr, dinv, offs, deg, epk, b3, NN, MPAD);
    // P4 = agg(H3) -> split [MPAD,128]
    k_agg<128, 128, false, true><<<aggBlocks, 256, 0, stream>>>(H3, nullptr, P4h, P4l, dinv, offs, deg, epk, nullptr, NN, MPAD);
    // H4 = relu(P4 @ W4 + b4) -> f32 [MPAD,200]
    k_gemm<true, 0><<<mB * 2, 256, 0, stream>>>(P4h, P4l, WT4h, WT4l, b4, H4, nullptr, nullptr, 200, 128, 2);

    k_reduce<<<(NN + 255) / 256, 256, 0, stream>>>(H4, gid, gsum, NN);
    k_final<<<4, 256, 0, stream>>>(gsum, gcnt, out);
}

// Round 7
// 665.959 us; speedup vs baseline: 1.3052x; 1.2868x over previous
//
#include <hip/hip_runtime.h>
#include <stdint.h>

typedef __attribute__((ext_vector_type(8))) short bf16x8;
typedef __attribute__((ext_vector_type(4))) float f32x4;

__device__ __forceinline__ float bf2f(ushort h) {
    union { uint u; float f; } v; v.u = ((uint)h) << 16; return v.f;
}
__device__ __forceinline__ ushort f2bf(float f) {
    union { float f; uint u; } v; v.f = f;
    uint u = v.u;
    return (ushort)((u + 0x7fffu + ((u >> 16) & 1u)) >> 16);
}

// async global->LDS, 16B per lane; LDS dest = wave-uniform base + lane*16
__device__ __forceinline__ void gll(const ushort* g, ushort* l) {
    __builtin_amdgcn_global_load_lds(
        (const __attribute__((address_space(1))) void*)g,
        (__attribute__((address_space(3))) void*)l, 16, 0, 0);
}

template <int VEC>
__device__ __forceinline__ void ldbf(const ushort* p, float* v) {
    if constexpr (VEC == 2) {
        uint u = *(const uint*)p;
        v[0] = bf2f((ushort)(u & 0xffffu));
        v[1] = bf2f((ushort)(u >> 16));
    } else {
        uint2 u = *(const uint2*)p;
        v[0] = bf2f((ushort)(u.x & 0xffffu));
        v[1] = bf2f((ushort)(u.x >> 16));
        v[2] = bf2f((ushort)(u.y & 0xffffu));
        v[3] = bf2f((ushort)(u.y >> 16));
    }
}

// ---------------- graph prep ----------------

__global__ void k_group(const uint4* __restrict__ x4, const uint4* __restrict__ nf4, int NN,
                        int* __restrict__ gid, int* __restrict__ gcnt) {
    __shared__ int cnt[4];
    if (threadIdx.x < 4) cnt[threadIdx.x] = 0;
    __syncthreads();
    int i = blockIdx.x * blockDim.x + threadIdx.x;
    if (i < NN) {
        const uint4* xr = x4 + (size_t)i * 25;  // 100 floats = 25 uint4
        bool e0 = true, e1 = true, e2 = true;
#pragma unroll 5
        for (int d = 0; d < 25; ++d) {
            uint4 v = xr[d];
            uint4 a = nf4[d], b = nf4[25 + d], c = nf4[50 + d];
            e0 &= (v.x == a.x) & (v.y == a.y) & (v.z == a.z) & (v.w == a.w);
            e1 &= (v.x == b.x) & (v.y == b.y) & (v.z == b.z) & (v.w == b.w);
            e2 &= (v.x == c.x) & (v.y == c.y) & (v.z == c.z) & (v.w == c.w);
        }
        int g = e0 ? 0 : (e1 ? 3 : (e2 ? 1 : 2));
        gid[i] = g;
        atomicAdd(&cnt[g], 1);
    }
    __syncthreads();
    if (threadIdx.x < 4 && cnt[threadIdx.x]) atomicAdd(&gcnt[threadIdx.x], cnt[threadIdx.x]);
}

__global__ void k_deg(const int* __restrict__ dst, int E, int* __restrict__ deg) {
    int e = blockIdx.x * blockDim.x + threadIdx.x;
    if (e < E) atomicAdd(&deg[dst[e]], 1);
}

__global__ void k_dinv(const int* __restrict__ deg, float* __restrict__ dinv, int NN) {
    int i = blockIdx.x * blockDim.x + threadIdx.x;
    if (i < NN) dinv[i] = 1.0f / sqrtf((float)(deg[i] + 1));  // +1 self loop
}

__global__ void k_scan(const int* __restrict__ deg, int* __restrict__ offs, int NN) {
    __shared__ int lds[1024];
    int t = threadIdx.x;
    int chunk = (NN + 1023) / 1024;
    int b0 = t * chunk;
    int b1 = min(b0 + chunk, NN);
    int s = 0;
    for (int i = b0; i < b1; ++i) s += deg[i];
    lds[t] = s;
    __syncthreads();
    for (int d = 1; d < 1024; d <<= 1) {
        int v = (t >= d) ? lds[t - d] : 0;
        __syncthreads();
        lds[t] += v;
        __syncthreads();
    }
    int excl = (t == 0) ? 0 : lds[t - 1];
    for (int i = b0; i < b1; ++i) { offs[i] = excl; excl += deg[i]; }
}

__global__ void k_fill(const int* __restrict__ src, const int* __restrict__ dst, int E,
                       const float* __restrict__ dinv, const int* __restrict__ offs,
                       int* __restrict__ cur, uint2* __restrict__ epk) {
    int e = blockIdx.x * blockDim.x + threadIdx.x;
    if (e >= E) return;
    int s = src[e], d = dst[e];
    int p = offs[d] + atomicAdd(&cur[d], 1);
    epk[p] = make_uint2((uint)s, __float_as_uint(dinv[s] * dinv[d]));
}

// ---------------- aggregation over bf16 rows (gather, wave per node) ----------------
// In/out bf16 single plane, f32 accumulate. D multiple of 64.

template <int D, bool BR>
__global__ void k_aggb(const ushort* __restrict__ H, ushort* __restrict__ outb,
                       const float* __restrict__ dinv, const int* __restrict__ offs,
                       const int* __restrict__ deg, const uint2* __restrict__ epk,
                       const float* __restrict__ bias, int NN, int NNpad) {
    constexpr int VEC = D / 64;
    int wid = (int)((blockIdx.x * blockDim.x + threadIdx.x) >> 6);
    int lane = threadIdx.x & 63;
    if (wid >= NNpad) return;
    int c0 = lane * VEC;
    ushort* op = outb + (size_t)wid * D + c0;
    if (wid >= NN) {  // zero pad rows
        if (VEC == 2) *(uint*)op = 0u;
        else *(uint2*)op = make_uint2(0u, 0u);
        return;
    }
    float acc[VEC], t0[VEC], t1[VEC];
    float di = dinv[wid];
    float sw = di * di;
    ldbf<VEC>(H + (size_t)wid * D + c0, t0);
#pragma unroll
    for (int j = 0; j < VEC; ++j) acc[j] = sw * t0[j];
    int e = offs[wid];
    int end = e + deg[wid];
    for (; e + 1 < end; e += 2) {
        uint2 q0 = epk[e], q1 = epk[e + 1];
        ldbf<VEC>(H + (size_t)q0.x * D + c0, t0);
        ldbf<VEC>(H + (size_t)q1.x * D + c0, t1);
        float w0 = __uint_as_float(q0.y), w1 = __uint_as_float(q1.y);
#pragma unroll
        for (int j = 0; j < VEC; ++j) acc[j] += w0 * t0[j];
#pragma unroll
        for (int j = 0; j < VEC; ++j) acc[j] += w1 * t1[j];
    }
    if (e < end) {
        uint2 q0 = epk[e];
        ldbf<VEC>(H + (size_t)q0.x * D + c0, t0);
        float w0 = __uint_as_float(q0.y);
#pragma unroll
        for (int j = 0; j < VEC; ++j) acc[j] += w0 * t0[j];
    }
    ushort r[VEC];
#pragma unroll
    for (int j = 0; j < VEC; ++j) {
        float v = acc[j];
        if (BR) v = fmaxf(v + bias[c0 + j], 0.0f);
        r[j] = f2bf(v);
    }
    if (VEC == 2) {
        *(uint*)op = (uint)r[0] | ((uint)r[1] << 16);
    } else {
        uint2 w;
        w.x = (uint)r[0] | ((uint)r[1] << 16);
        w.y = (uint)r[2] | ((uint)r[3] << 16);
        *(uint2*)op = w;
    }
}

// Layer-1 aggregation: f32 x rows (D=100) -> bf16 P1 [NNpad,128], zero-padded cols.
__global__ void k_agg1(const float* __restrict__ x, ushort* __restrict__ outb,
                       const float* __restrict__ dinv, const int* __restrict__ offs,
                       const int* __restrict__ deg, const uint2* __restrict__ epk,
                       int NN, int NNpad) {
    constexpr int D = 100, DPAD = 128, VEC = 2;
    int wid = (int)((blockIdx.x * blockDim.x + threadIdx.x) >> 6);
    int lane = threadIdx.x & 63;
    if (wid >= NNpad) return;
    int c0 = lane * VEC;
    ushort* op = outb + (size_t)wid * DPAD + c0;
    bool act = (c0 + VEC <= D);
    if (wid >= NN || !act) {
        if (wid < NNpad) *(uint*)op = 0u;
        return;
    }
    float acc[VEC];
    float di = dinv[wid];
    float sw = di * di;
    {
        const float* hp = x + (size_t)wid * D + c0;
#pragma unroll
        for (int j = 0; j < VEC; ++j) acc[j] = sw * hp[j];
    }
    int e = offs[wid];
    int end = e + deg[wid];
    for (; e + 1 < end; e += 2) {
        uint2 q0 = epk[e], q1 = epk[e + 1];
        const float* h0 = x + (size_t)q0.x * D + c0;
        const float* h1 = x + (size_t)q1.x * D + c0;
        float w0 = __uint_as_float(q0.y), w1 = __uint_as_float(q1.y);
#pragma unroll
        for (int j = 0; j < VEC; ++j) acc[j] += w0 * h0[j];
#pragma unroll
        for (int j = 0; j < VEC; ++j) acc[j] += w1 * h1[j];
    }
    if (e < end) {
        uint2 q0 = epk[e];
        const float* h0 = x + (size_t)q0.x * D + c0;
        float w0 = __uint_as_float(q0.y);
#pragma unroll
        for (int j = 0; j < VEC; ++j) acc[j] += w0 * h0[j];
    }
    uint w = (uint)f2bf(acc[0]) | ((uint)f2bf(acc[1]) << 16);
    *(uint*)op = w;
}

// ---------------- MFMA GEMM: A bf16 single plane, W hi/lo split (2-term) ----------------
// C[M,N] = A[M,K] @ BT[N,K]^T (+bias, relu). Block tile 128x128, 4 waves (64x64).
// Staging: wave0/1 -> A halves, wave2 -> Bh, wave3 -> Bl (global_load_lds w16).
// OUT: 0 = f32 to Cf, 1 = bf16 to Cb. LDS-buffered coalesced epilogue.

template <bool BR, int OUT>
__global__ __launch_bounds__(256) void k_gemm(
        const ushort* __restrict__ A,
        const ushort* __restrict__ Bh, const ushort* __restrict__ Bl,
        const float* __restrict__ bias,
        float* __restrict__ Cf, ushort* __restrict__ Cb,
        int Nc, int K, int tNb) {
    __shared__ union {
        ushort st[3][128 * 32];
        float epi[64 * 132];
    } sm;
    int bm = blockIdx.x / tNb, bn = blockIdx.x % tNb;
    int m0 = bm * 128, n0 = bn * 128;
    int wv = threadIdx.x >> 6, lane = threadIdx.x & 63;
    int l15 = lane & 15, quad = lane >> 4;
    const ushort* gsrc;
    ushort* ldst;
    int ng;
    if (wv == 0)      { gsrc = A  + (size_t)m0 * K;        ldst = sm.st[0];        ng = 4; }
    else if (wv == 1) { gsrc = A  + (size_t)(m0 + 64) * K; ldst = sm.st[0] + 2048; ng = 4; }
    else if (wv == 2) { gsrc = Bh + (size_t)n0 * K;        ldst = sm.st[1];        ng = 8; }
    else              { gsrc = Bl + (size_t)n0 * K;        ldst = sm.st[2];        ng = 8; }
    const ushort* gBase = gsrc + (size_t)(lane >> 2) * K + (lane & 3) * 8;
    int wm = (wv >> 1) * 64, wn = (wv & 1) * 64;
    const ushort* sA_ = sm.st[0];
    const ushort* sBh_ = sm.st[1];
    const ushort* sBl_ = sm.st[2];
    f32x4 acc[4][4] = {};
    for (int k0 = 0; k0 < K; k0 += 32) {
        for (int i = 0; i < ng; ++i)
            gll(gBase + (size_t)(16 * i) * K + k0, ldst + i * 512);
        __syncthreads();
        bf16x8 Af[4], Bfh[4], Bfl[4];
#pragma unroll
        for (int i = 0; i < 4; ++i) {
            int ra = (wm + 16 * i + l15) * 32 + quad * 8;
            int rb = (wn + 16 * i + l15) * 32 + quad * 8;
            Af[i]  = *(const bf16x8*)(sA_ + ra);
            Bfh[i] = *(const bf16x8*)(sBh_ + rb);
            Bfl[i] = *(const bf16x8*)(sBl_ + rb);
        }
#pragma unroll
        for (int mi = 0; mi < 4; ++mi)
#pragma unroll
            for (int ni = 0; ni < 4; ++ni) {
                acc[mi][ni] = __builtin_amdgcn_mfma_f32_16x16x32_bf16(Af[mi], Bfh[ni], acc[mi][ni], 0, 0, 0);
                acc[mi][ni] = __builtin_amdgcn_mfma_f32_16x16x32_bf16(Af[mi], Bfl[ni], acc[mi][ni], 0, 0, 0);
            }
        __syncthreads();
    }
    float bia[4] = {0.f, 0.f, 0.f, 0.f};
    if (BR) {
#pragma unroll
        for (int ni = 0; ni < 4; ++ni) {
            int col = n0 + wn + 16 * ni + l15;
            if (col < Nc) bia[ni] = bias[col];
        }
    }
    float* epi = sm.epi;
    int t = threadIdx.x;
    for (int half = 0; half < 2; ++half) {
        if ((wv >> 1) == half) {
#pragma unroll
            for (int mi = 0; mi < 4; ++mi)
#pragma unroll
                for (int r = 0; r < 4; ++r) {
                    int rl = mi * 16 + quad * 4 + r;
#pragma unroll
                    for (int ni = 0; ni < 4; ++ni) {
                        float v = acc[mi][ni][r];
                        if (BR) v = fmaxf(v + bia[ni], 0.0f);
                        epi[rl * 132 + wn + ni * 16 + l15] = v;
                    }
                }
        }
        __syncthreads();
#pragma unroll
        for (int j = 0; j < 16; ++j) {
            int e = (j * 256 + t) * 2;
            int rl = e >> 7, cl = e & 127;
            int grow = m0 + half * 64 + rl;
            int gcol = n0 + cl;
            float v0 = epi[rl * 132 + cl];
            float v1 = epi[rl * 132 + cl + 1];
            if (OUT == 0) {
                if (gcol < Nc) {
                    float2 w; w.x = v0; w.y = v1;
                    *(float2*)&Cf[(size_t)grow * Nc + gcol] = w;
                }
            } else {
                *(uint*)&Cb[(size_t)grow * Nc + gcol] = (uint)f2bf(v0) | ((uint)f2bf(v1) << 16);
            }
        }
        __syncthreads();
    }
}

// ---------------- weight transpose + split: WT[NP][KP] hi/lo bf16, zeros outside ----------------

__global__ void k_tr2(const float* __restrict__ W, ushort* __restrict__ WTh, ushort* __restrict__ WTl,
                      int K, int Nc, int KP, int NP) {
    int idx = blockIdx.x * blockDim.x + threadIdx.x;
    if (idx >= NP * KP) return;
    int n = idx / KP, k = idx % KP;
    float w = (n < Nc && k < K) ? W[(size_t)k * Nc + n] : 0.0f;
    ushort hi = f2bf(w);
    ushort lo = f2bf(w - bf2f(hi));
    WTh[idx] = hi;
    WTl[idx] = lo;
}

// ---------------- group reduce / final ----------------

__global__ void k_reduce(const float* __restrict__ H4, const int* __restrict__ gid,
                         float* __restrict__ gsum, int NN) {
    int d = threadIdx.x;
    if (d >= 200) return;
    int n0 = blockIdx.x * 256;
    int n1 = min(n0 + 256, NN);
    float r0 = 0.f, r1 = 0.f, r2 = 0.f, r3 = 0.f;
    for (int n = n0; n < n1; ++n) {
        int g = gid[n];
        float v = H4[(size_t)n * 200 + d];
        r0 += (g == 0) ? v : 0.f;
        r1 += (g == 1) ? v : 0.f;
        r2 += (g == 2) ? v : 0.f;
        r3 += (g == 3) ? v : 0.f;
    }
    atomicAdd(&gsum[0 * 200 + d], r0);
    atomicAdd(&gsum[1 * 200 + d], r1);
    atomicAdd(&gsum[2 * 200 + d], r2);
    atomicAdd(&gsum[3 * 200 + d], r3);
}

__global__ void k_final(const float* __restrict__ gsum, const int* __restrict__ gcnt,
                        float* __restrict__ out) {
    int j = blockIdx.x * blockDim.x + threadIdx.x;
    if (j >= 800) return;
    int g = j / 200;
    int c = gcnt[g];
    out[j] = (c > 0) ? gsum[j] / (float)c : 0.0f;
}

// ---------------- launch ----------------

extern "C" void kernel_launch(void* const* d_in, const int* in_sizes, int n_in,
                              void* d_out, int out_size, void* d_ws, size_t ws_size,
                              hipStream_t stream) {
    const float* x  = (const float*)d_in[0];
    const float* nf = (const float*)d_in[1];
    const int* ei   = (const int*)d_in[2];
    const float* W1 = (const float*)d_in[3];
    const float* b1 = (const float*)d_in[4];
    const float* W2 = (const float*)d_in[5];
    const float* b2 = (const float*)d_in[6];
    const float* W3 = (const float*)d_in[7];
    const float* b3 = (const float*)d_in[8];
    const float* W4 = (const float*)d_in[9];
    const float* b4 = (const float*)d_in[10];
    float* out = (float*)d_out;

    const int NN = in_sizes[0] / 100;  // 50000
    const int E  = in_sizes[2] / 2;    // 800000
    const int MPAD = ((NN + 127) / 128) * 128;  // 50048
    const int* src = ei;
    const int* dst = ei + E;

    char* p = (char*)d_ws;
    auto alloc = [&](size_t bytes) -> char* {
        char* r = p;
        p += (bytes + 255) & ~(size_t)255;
        return r;
    };
    char* zz = p;
    int*   deg  = (int*)alloc((size_t)NN * 4);
    int*   cur  = (int*)alloc((size_t)NN * 4);
    int*   gcnt = (int*)alloc(256);
    float* gsum = (float*)alloc(800 * 4);
    size_t zz_bytes = (size_t)(p - zz);
    float* dinv = (float*)alloc((size_t)NN * 4);
    int*   offs = (int*)alloc((size_t)NN * 4);
    int*   gid  = (int*)alloc((size_t)NN * 4);
    uint2* epk  = (uint2*)alloc((size_t)E * 8);
    ushort* WT1h = (ushort*)alloc((size_t)512 * 128 * 2);
    ushort* WT1l = (ushort*)alloc((size_t)512 * 128 * 2);
    ushort* WT2h = (ushort*)alloc((size_t)256 * 512 * 2);
    ushort* WT2l = (ushort*)alloc((size_t)256 * 512 * 2);
    ushort* WT3h = (ushort*)alloc((size_t)128 * 256 * 2);
    ushort* WT3l = (ushort*)alloc((size_t)128 * 256 * 2);
    ushort* WT4h = (ushort*)alloc((size_t)256 * 128 * 2);
    ushort* WT4l = (ushort*)alloc((size_t)256 * 128 * 2);
    ushort* P1 = (ushort*)alloc((size_t)MPAD * 128 * 2);
    ushort* H1 = (ushort*)alloc((size_t)MPAD * 512 * 2);
    ushort* T2 = (ushort*)alloc((size_t)MPAD * 256 * 2);
    ushort* H2 = (ushort*)alloc((size_t)MPAD * 256 * 2);
    ushort* T3 = (ushort*)alloc((size_t)MPAD * 128 * 2);
    ushort* H3 = (ushort*)alloc((size_t)MPAD * 128 * 2);
    ushort* P4 = (ushort*)alloc((size_t)MPAD * 128 * 2);
    float*  H4 = (float*)alloc((size_t)MPAD * 200 * 4);

    hipMemsetAsync(zz, 0, zz_bytes, stream);

    k_group<<<(NN + 255) / 256, 256, 0, stream>>>((const uint4*)x, (const uint4*)nf, NN, gid, gcnt);
    k_deg<<<(E + 255) / 256, 256, 0, stream>>>(dst, E, deg);
    k_dinv<<<(NN + 255) / 256, 256, 0, stream>>>(deg, dinv, NN);
    k_scan<<<1, 1024, 0, stream>>>(deg, offs, NN);
    k_fill<<<(E + 255) / 256, 256, 0, stream>>>(src, dst, E, dinv, offs, cur, epk);

    k_tr2<<<(512 * 128 + 255) / 256, 256, 0, stream>>>(W1, WT1h, WT1l, 100, 512, 128, 512);
    k_tr2<<<(256 * 512 + 255) / 256, 256, 0, stream>>>(W2, WT2h, WT2l, 512, 256, 512, 256);
    k_tr2<<<(128 * 256 + 255) / 256, 256, 0, stream>>>(W3, WT3h, WT3l, 256, 128, 256, 128);
    k_tr2<<<(256 * 128 + 255) / 256, 256, 0, stream>>>(W4, WT4h, WT4l, 128, 200, 128, 256);

    int aggBlocks = MPAD / 4;  // one wave per node incl. pad rows
    int mB = MPAD / 128;

    // P1 = agg(x) -> bf16 [MPAD,128]
    k_agg1<<<aggBlocks, 256, 0, stream>>>(x, P1, dinv, offs, deg, epk, NN, MPAD);
    // H1 = relu(P1 @ W1 + b1) -> bf16 [MPAD,512]
    k_gemm<true, 1><<<mB * 4, 256, 0, stream>>>(P1, WT1h, WT1l, b1, nullptr, H1, 512, 128, 4);
    // T2 = H1 @ W2 -> bf16 [MPAD,256]
    k_gemm<false, 1><<<mB * 2, 256, 0, stream>>>(H1, WT2h, WT2l, nullptr, nullptr, T2, 256, 512, 2);
    // H2 = relu(agg(T2) + b2) -> bf16 [MPAD,256]
    k_aggb<256, true><<<aggBlocks, 256, 0, stream>>>(T2, H2, dinv, offs, deg, epk, b2, NN, MPAD);
    // T3 = H2 @ W3 -> bf16 [MPAD,128]
    k_gemm<false, 1><<<mB * 1, 256, 0, stream>>>(H2, WT3h, WT3l, nullptr, nullptr, T3, 128, 256, 1);
    // H3 = relu(agg(T3) + b3) -> bf16 [MPAD,128]
    k_aggb<128, true><<<aggBlocks, 256, 0, stream>>>(T3, H3, dinv, offs, deg, epk, b3, NN, MPAD);
    // P4 = agg(H3) -> bf16 [MPAD,128]
    k_aggb<128, false><<<aggBlocks, 256, 0, stream>>>(H3, P4, dinv, offs, deg, epk, nullptr, NN, MPAD);
    // H4 = relu(P4 @ W4 + b4) -> f32 [MPAD,200]
    k_gemm<true, 0><<<mB * 2, 256, 0, stream>>>(P4, WT4h, WT4l, b4, H4, nullptr, 200, 128, 2);

    k_reduce<<<(NN + 255) / 256, 256, 0, stream>>>(H4, gid, gsum, NN);
    k_final<<<4, 256, 0, stream>>>(gsum, gcnt, out);
}

// Round 8
// 600.003 us; speedup vs baseline: 1.4487x; 1.1099x over previous
//
#include <hip/hip_runtime.h>
#include <stdint.h>

typedef __attribute__((ext_vector_type(8))) short bf16x8;
typedef __attribute__((ext_vector_type(4))) float f32x4;

__device__ __forceinline__ float bf2f(ushort h) {
    union { uint u; float f; } v; v.u = ((uint)h) << 16; return v.f;
}
__device__ __forceinline__ ushort f2bf(float f) {
    union { float f; uint u; } v; v.f = f;
    uint u = v.u;
    return (ushort)((u + 0x7fffu + ((u >> 16) & 1u)) >> 16);
}

// async global->LDS, 16B per lane; LDS dest = wave-uniform base + lane*16
__device__ __forceinline__ void gll(const ushort* g, ushort* l) {
    __builtin_amdgcn_global_load_lds(
        (const __attribute__((address_space(1))) void*)g,
        (__attribute__((address_space(3))) void*)l, 16, 0, 0);
}

template <int VEC>
__device__ __forceinline__ void ldbf(const ushort* p, float* v) {
    if constexpr (VEC == 2) {
        uint u = *(const uint*)p;
        v[0] = bf2f((ushort)(u & 0xffffu));
        v[1] = bf2f((ushort)(u >> 16));
    } else {
        uint2 u = *(const uint2*)p;
        v[0] = bf2f((ushort)(u.x & 0xffffu));
        v[1] = bf2f((ushort)(u.x >> 16));
        v[2] = bf2f((ushort)(u.y & 0xffffu));
        v[3] = bf2f((ushort)(u.y >> 16));
    }
}

// ---------------- graph prep ----------------

__global__ void k_group(const uint4* __restrict__ x4, const uint4* __restrict__ nf4, int NN,
                        int* __restrict__ gid, int* __restrict__ gcnt) {
    __shared__ int cnt[4];
    if (threadIdx.x < 4) cnt[threadIdx.x] = 0;
    __syncthreads();
    int i = blockIdx.x * blockDim.x + threadIdx.x;
    if (i < NN) {
        const uint4* xr = x4 + (size_t)i * 25;  // 100 floats = 25 uint4
        bool e0 = true, e1 = true, e2 = true;
#pragma unroll 5
        for (int d = 0; d < 25; ++d) {
            uint4 v = xr[d];
            uint4 a = nf4[d], b = nf4[25 + d], c = nf4[50 + d];
            e0 &= (v.x == a.x) & (v.y == a.y) & (v.z == a.z) & (v.w == a.w);
            e1 &= (v.x == b.x) & (v.y == b.y) & (v.z == b.z) & (v.w == b.w);
            e2 &= (v.x == c.x) & (v.y == c.y) & (v.z == c.z) & (v.w == c.w);
        }
        int g = e0 ? 0 : (e1 ? 3 : (e2 ? 1 : 2));
        gid[i] = g;
        atomicAdd(&cnt[g], 1);
    }
    __syncthreads();
    if (threadIdx.x < 4 && cnt[threadIdx.x]) atomicAdd(&gcnt[threadIdx.x], cnt[threadIdx.x]);
}

// x (f32, D=100) -> xb (bf16, 128 cols, zero-padded cols), wave per row
__global__ void k_xb(const float* __restrict__ x, ushort* __restrict__ xb, int NN) {
    int wid = (int)((blockIdx.x * blockDim.x + threadIdx.x) >> 6);
    int lane = threadIdx.x & 63;
    if (wid >= NN) return;
    int c0 = lane * 2;
    uint w = 0u;
    if (c0 + 2 <= 100) {
        const float* hp = x + (size_t)wid * 100 + c0;
        w = (uint)f2bf(hp[0]) | ((uint)f2bf(hp[1]) << 16);
    }
    *(uint*)&xb[(size_t)wid * 128 + c0] = w;
}

__global__ void k_deg(const int* __restrict__ dst, int E, int* __restrict__ deg) {
    int e = blockIdx.x * blockDim.x + threadIdx.x;
    if (e < E) atomicAdd(&deg[dst[e]], 1);
}

__global__ void k_dinv(const int* __restrict__ deg, float* __restrict__ dinv, int NN) {
    int i = blockIdx.x * blockDim.x + threadIdx.x;
    if (i < NN) dinv[i] = 1.0f / sqrtf((float)(deg[i] + 1));  // +1 self loop
}

// 3-phase parallel exclusive scan of deg -> offs
__global__ void k_scanA(const int* __restrict__ deg, int* __restrict__ offs,
                        int* __restrict__ bsum, int NN) {
    __shared__ int lds[256];
    int t = threadIdx.x;
    int i = blockIdx.x * 256 + t;
    int v = (i < NN) ? deg[i] : 0;
    lds[t] = v;
    __syncthreads();
    for (int d = 1; d < 256; d <<= 1) {
        int u = (t >= d) ? lds[t - d] : 0;
        __syncthreads();
        lds[t] += u;
        __syncthreads();
    }
    if (i < NN) offs[i] = lds[t] - v;  // block-local exclusive
    if (t == 255) bsum[blockIdx.x] = lds[255];
}

__global__ void k_scanB(int* __restrict__ bsum, int nb) {
    __shared__ int lds[256];
    int t = threadIdx.x;
    int v = (t < nb) ? bsum[t] : 0;
    lds[t] = v;
    __syncthreads();
    for (int d = 1; d < 256; d <<= 1) {
        int u = (t >= d) ? lds[t - d] : 0;
        __syncthreads();
        lds[t] += u;
        __syncthreads();
    }
    if (t < nb) bsum[t] = lds[t] - v;  // exclusive block prefix
}

__global__ void k_scanC(int* __restrict__ offs, const int* __restrict__ bsum, int NN) {
    int i = blockIdx.x * 256 + threadIdx.x;
    if (i < NN) offs[i] += bsum[blockIdx.x];
}

__global__ void k_fill(const int* __restrict__ src, const int* __restrict__ dst, int E,
                       const float* __restrict__ dinv, const int* __restrict__ offs,
                       int* __restrict__ cur, uint2* __restrict__ epk) {
    int e = blockIdx.x * blockDim.x + threadIdx.x;
    if (e >= E) return;
    int s = src[e], d = dst[e];
    int p = offs[d] + atomicAdd(&cur[d], 1);
    epk[p] = make_uint2((uint)s, __float_as_uint(dinv[s] * dinv[d]));
}

// ---------------- aggregation over bf16 rows (gather, wave per node) ----------------
// In/out bf16 single plane, f32 accumulate. D multiple of 64.
// SELF: include self-loop term from H (requires H row valid for wid<NN).

template <int D, bool BR>
__global__ void k_aggb(const ushort* __restrict__ H, ushort* __restrict__ outb,
                       const float* __restrict__ dinv, const int* __restrict__ offs,
                       const int* __restrict__ deg, const uint2* __restrict__ epk,
                       const float* __restrict__ bias, int NN, int NNpad) {
    constexpr int VEC = D / 64;
    int wid = (int)((blockIdx.x * blockDim.x + threadIdx.x) >> 6);
    int lane = threadIdx.x & 63;
    if (wid >= NNpad) return;
    int c0 = lane * VEC;
    ushort* op = outb + (size_t)wid * D + c0;
    if (wid >= NN) {  // zero pad rows
        if (VEC == 2) *(uint*)op = 0u;
        else *(uint2*)op = make_uint2(0u, 0u);
        return;
    }
    float acc[VEC], t0[VEC], t1[VEC];
    float di = dinv[wid];
    float sw = di * di;
    ldbf<VEC>(H + (size_t)wid * D + c0, t0);
#pragma unroll
    for (int j = 0; j < VEC; ++j) acc[j] = sw * t0[j];
    int e = offs[wid];
    int end = e + deg[wid];
    for (; e + 1 < end; e += 2) {
        uint2 q0 = epk[e], q1 = epk[e + 1];
        ldbf<VEC>(H + (size_t)q0.x * D + c0, t0);
        ldbf<VEC>(H + (size_t)q1.x * D + c0, t1);
        float w0 = __uint_as_float(q0.y), w1 = __uint_as_float(q1.y);
#pragma unroll
        for (int j = 0; j < VEC; ++j) acc[j] += w0 * t0[j];
#pragma unroll
        for (int j = 0; j < VEC; ++j) acc[j] += w1 * t1[j];
    }
    if (e < end) {
        uint2 q0 = epk[e];
        ldbf<VEC>(H + (size_t)q0.x * D + c0, t0);
        float w0 = __uint_as_float(q0.y);
#pragma unroll
        for (int j = 0; j < VEC; ++j) acc[j] += w0 * t0[j];
    }
    ushort r[VEC];
#pragma unroll
    for (int j = 0; j < VEC; ++j) {
        float v = acc[j];
        if (BR) v = fmaxf(v + bias[c0 + j], 0.0f);
        r[j] = f2bf(v);
    }
    if (VEC == 2) {
        *(uint*)op = (uint)r[0] | ((uint)r[1] << 16);
    } else {
        uint2 w;
        w.x = (uint)r[0] | ((uint)r[1] << 16);
        w.y = (uint)r[2] | ((uint)r[3] << 16);
        *(uint2*)op = w;
    }
}

// ---------------- MFMA GEMM: A bf16 single plane, W hi/lo split (2-term) ----------------
// C[M,N] = A[M,K] @ BT[N,K]^T (+bias, relu). Block tile 128x128, 4 waves (64x64).
// Staging: wave0/1 -> A halves, wave2 -> Bh, wave3 -> Bl (global_load_lds w16).
// OUT: 0 = f32 to Cf, 1 = bf16 to Cb. LDS-buffered coalesced epilogue.

template <bool BR, int OUT>
__global__ __launch_bounds__(256) void k_gemm(
        const ushort* __restrict__ A,
        const ushort* __restrict__ Bh, const ushort* __restrict__ Bl,
        const float* __restrict__ bias,
        float* __restrict__ Cf, ushort* __restrict__ Cb,
        int Nc, int K, int tNb) {
    __shared__ union {
        ushort st[3][128 * 32];
        float epi[64 * 132];
    } sm;
    int bm = blockIdx.x / tNb, bn = blockIdx.x % tNb;
    int m0 = bm * 128, n0 = bn * 128;
    int wv = threadIdx.x >> 6, lane = threadIdx.x & 63;
    int l15 = lane & 15, quad = lane >> 4;
    const ushort* gsrc;
    ushort* ldst;
    int ng;
    if (wv == 0)      { gsrc = A  + (size_t)m0 * K;        ldst = sm.st[0];        ng = 4; }
    else if (wv == 1) { gsrc = A  + (size_t)(m0 + 64) * K; ldst = sm.st[0] + 2048; ng = 4; }
    else if (wv == 2) { gsrc = Bh + (size_t)n0 * K;        ldst = sm.st[1];        ng = 8; }
    else              { gsrc = Bl + (size_t)n0 * K;        ldst = sm.st[2];        ng = 8; }
    const ushort* gBase = gsrc + (size_t)(lane >> 2) * K + (lane & 3) * 8;
    int wm = (wv >> 1) * 64, wn = (wv & 1) * 64;
    const ushort* sA_ = sm.st[0];
    const ushort* sBh_ = sm.st[1];
    const ushort* sBl_ = sm.st[2];
    f32x4 acc[4][4] = {};
    for (int k0 = 0; k0 < K; k0 += 32) {
        for (int i = 0; i < ng; ++i)
            gll(gBase + (size_t)(16 * i) * K + k0, ldst + i * 512);
        __syncthreads();
        bf16x8 Af[4], Bfh[4], Bfl[4];
#pragma unroll
        for (int i = 0; i < 4; ++i) {
            int ra = (wm + 16 * i + l15) * 32 + quad * 8;
            int rb = (wn + 16 * i + l15) * 32 + quad * 8;
            Af[i]  = *(const bf16x8*)(sA_ + ra);
            Bfh[i] = *(const bf16x8*)(sBh_ + rb);
            Bfl[i] = *(const bf16x8*)(sBl_ + rb);
        }
#pragma unroll
        for (int mi = 0; mi < 4; ++mi)
#pragma unroll
            for (int ni = 0; ni < 4; ++ni) {
                acc[mi][ni] = __builtin_amdgcn_mfma_f32_16x16x32_bf16(Af[mi], Bfh[ni], acc[mi][ni], 0, 0, 0);
                acc[mi][ni] = __builtin_amdgcn_mfma_f32_16x16x32_bf16(Af[mi], Bfl[ni], acc[mi][ni], 0, 0, 0);
            }
        __syncthreads();
    }
    float bia[4] = {0.f, 0.f, 0.f, 0.f};
    if (BR) {
#pragma unroll
        for (int ni = 0; ni < 4; ++ni) {
            int col = n0 + wn + 16 * ni + l15;
            if (col < Nc) bia[ni] = bias[col];
        }
    }
    float* epi = sm.epi;
    int t = threadIdx.x;
    for (int half = 0; half < 2; ++half) {
        if ((wv >> 1) == half) {
#pragma unroll
            for (int mi = 0; mi < 4; ++mi)
#pragma unroll
                for (int r = 0; r < 4; ++r) {
                    int rl = mi * 16 + quad * 4 + r;
#pragma unroll
                    for (int ni = 0; ni < 4; ++ni) {
                        float v = acc[mi][ni][r];
                        if (BR) v = fmaxf(v + bia[ni], 0.0f);
                        epi[rl * 132 + wn + ni * 16 + l15] = v;
                    }
                }
        }
        __syncthreads();
#pragma unroll
        for (int j = 0; j < 16; ++j) {
            int e = (j * 256 + t) * 2;
            int rl = e >> 7, cl = e & 127;
            int grow = m0 + half * 64 + rl;
            int gcol = n0 + cl;
            float v0 = epi[rl * 132 + cl];
            float v1 = epi[rl * 132 + cl + 1];
            if (OUT == 0) {
                if (gcol < Nc) {
                    float2 w; w.x = v0; w.y = v1;
                    *(float2*)&Cf[(size_t)grow * Nc + gcol] = w;
                }
            } else {
                *(uint*)&Cb[(size_t)grow * Nc + gcol] = (uint)f2bf(v0) | ((uint)f2bf(v1) << 16);
            }
        }
        __syncthreads();
    }
}

// ---------------- weight transpose + split: WT[NP][KP] hi/lo bf16, zeros outside ----------------

__global__ void k_tr2(const float* __restrict__ W, ushort* __restrict__ WTh, ushort* __restrict__ WTl,
                      int K, int Nc, int KP, int NP) {
    int idx = blockIdx.x * blockDim.x + threadIdx.x;
    if (idx >= NP * KP) return;
    int n = idx / KP, k = idx % KP;
    float w = (n < Nc && k < K) ? W[(size_t)k * Nc + n] : 0.0f;
    ushort hi = f2bf(w);
    ushort lo = f2bf(w - bf2f(hi));
    WTh[idx] = hi;
    WTl[idx] = lo;
}

// ---------------- group reduce / final ----------------

__global__ void k_reduce(const float* __restrict__ H4, const int* __restrict__ gid,
                         float* __restrict__ gsum, int NN) {
    int d = threadIdx.x;
    if (d >= 200) return;
    int n0 = blockIdx.x * 256;
    int n1 = min(n0 + 256, NN);
    float r0 = 0.f, r1 = 0.f, r2 = 0.f, r3 = 0.f;
    for (int n = n0; n < n1; ++n) {
        int g = gid[n];
        float v = H4[(size_t)n * 200 + d];
        r0 += (g == 0) ? v : 0.f;
        r1 += (g == 1) ? v : 0.f;
        r2 += (g == 2) ? v : 0.f;
        r3 += (g == 3) ? v : 0.f;
    }
    atomicAdd(&gsum[0 * 200 + d], r0);
    atomicAdd(&gsum[1 * 200 + d], r1);
    atomicAdd(&gsum[2 * 200 + d], r2);
    atomicAdd(&gsum[3 * 200 + d], r3);
}

__global__ void k_final(const float* __restrict__ gsum, const int* __restrict__ gcnt,
                        float* __restrict__ out) {
    int j = blockIdx.x * blockDim.x + threadIdx.x;
    if (j >= 800) return;
    int g = j / 200;
    int c = gcnt[g];
    out[j] = (c > 0) ? gsum[j] / (float)c : 0.0f;
}

// ---------------- launch ----------------

extern "C" void kernel_launch(void* const* d_in, const int* in_sizes, int n_in,
                              void* d_out, int out_size, void* d_ws, size_t ws_size,
                              hipStream_t stream) {
    const float* x  = (const float*)d_in[0];
    const float* nf = (const float*)d_in[1];
    const int* ei   = (const int*)d_in[2];
    const float* W1 = (const float*)d_in[3];
    const float* b1 = (const float*)d_in[4];
    const float* W2 = (const float*)d_in[5];
    const float* b2 = (const float*)d_in[6];
    const float* W3 = (const float*)d_in[7];
    const float* b3 = (const float*)d_in[8];
    const float* W4 = (const float*)d_in[9];
    const float* b4 = (const float*)d_in[10];
    float* out = (float*)d_out;

    const int NN = in_sizes[0] / 100;  // 50000
    const int E  = in_sizes[2] / 2;    // 800000
    const int MPAD = ((NN + 127) / 128) * 128;  // 50048
    const int NB = (NN + 255) / 256;   // scan blocks (196 <= 256)
    const int* src = ei;
    const int* dst = ei + E;

    char* p = (char*)d_ws;
    auto alloc = [&](size_t bytes) -> char* {
        char* r = p;
        p += (bytes + 255) & ~(size_t)255;
        return r;
    };
    char* zz = p;
    int*   deg  = (int*)alloc((size_t)NN * 4);
    int*   cur  = (int*)alloc((size_t)NN * 4);
    int*   gcnt = (int*)alloc(256);
    float* gsum = (float*)alloc(800 * 4);
    size_t zz_bytes = (size_t)(p - zz);
    float* dinv = (float*)alloc((size_t)NN * 4);
    int*   offs = (int*)alloc((size_t)NN * 4);
    int*   bsum = (int*)alloc(1024);
    int*   gid  = (int*)alloc((size_t)NN * 4);
    uint2* epk  = (uint2*)alloc((size_t)E * 8);
    ushort* WT1h = (ushort*)alloc((size_t)512 * 128 * 2);
    ushort* WT1l = (ushort*)alloc((size_t)512 * 128 * 2);
    ushort* WT2h = (ushort*)alloc((size_t)256 * 512 * 2);
    ushort* WT2l = (ushort*)alloc((size_t)256 * 512 * 2);
    ushort* WT3h = (ushort*)alloc((size_t)128 * 256 * 2);
    ushort* WT3l = (ushort*)alloc((size_t)128 * 256 * 2);
    ushort* WT4h = (ushort*)alloc((size_t)256 * 128 * 2);
    ushort* WT4l = (ushort*)alloc((size_t)256 * 128 * 2);
    ushort* xb = (ushort*)alloc((size_t)NN * 128 * 2);
    ushort* P1 = (ushort*)alloc((size_t)MPAD * 128 * 2);
    ushort* H1 = (ushort*)alloc((size_t)MPAD * 512 * 2);
    ushort* T2 = (ushort*)alloc((size_t)MPAD * 256 * 2);
    ushort* H2 = (ushort*)alloc((size_t)MPAD * 256 * 2);
    ushort* T3 = (ushort*)alloc((size_t)MPAD * 128 * 2);
    ushort* H3 = (ushort*)alloc((size_t)MPAD * 128 * 2);
    ushort* P4 = (ushort*)alloc((size_t)MPAD * 128 * 2);
    float*  H4 = (float*)alloc((size_t)MPAD * 200 * 4);

    hipMemsetAsync(zz, 0, zz_bytes, stream);

    k_group<<<(NN + 255) / 256, 256, 0, stream>>>((const uint4*)x, (const uint4*)nf, NN, gid, gcnt);
    k_xb<<<(NN + 3) / 4, 256, 0, stream>>>(x, xb, NN);
    k_deg<<<(E + 255) / 256, 256, 0, stream>>>(dst, E, deg);
    k_dinv<<<(NN + 255) / 256, 256, 0, stream>>>(deg, dinv, NN);
    k_scanA<<<NB, 256, 0, stream>>>(deg, offs, bsum, NN);
    k_scanB<<<1, 256, 0, stream>>>(bsum, NB);
    k_scanC<<<NB, 256, 0, stream>>>(offs, bsum, NN);
    k_fill<<<(E + 255) / 256, 256, 0, stream>>>(src, dst, E, dinv, offs, cur, epk);

    k_tr2<<<(512 * 128 + 255) / 256, 256, 0, stream>>>(W1, WT1h, WT1l, 100, 512, 128, 512);
    k_tr2<<<(256 * 512 + 255) / 256, 256, 0, stream>>>(W2, WT2h, WT2l, 512, 256, 512, 256);
    k_tr2<<<(128 * 256 + 255) / 256, 256, 0, stream>>>(W3, WT3h, WT3l, 256, 128, 256, 128);
    k_tr2<<<(256 * 128 + 255) / 256, 256, 0, stream>>>(W4, WT4h, WT4l, 128, 200, 128, 256);

    int aggBlocks = MPAD / 4;  // one wave per node incl. pad rows
    int mB = MPAD / 128;

    // P1 = agg(xb) -> bf16 [MPAD,128]
    k_aggb<128, false><<<aggBlocks, 256, 0, stream>>>(xb, P1, dinv, offs, deg, epk, nullptr, NN, MPAD);
    // H1 = relu(P1 @ W1 + b1) -> bf16 [MPAD,512]
    k_gemm<true, 1><<<mB * 4, 256, 0, stream>>>(P1, WT1h, WT1l, b1, nullptr, H1, 512, 128, 4);
    // T2 = H1 @ W2 -> bf16 [MPAD,256]
    k_gemm<false, 1><<<mB * 2, 256, 0, stream>>>(H1, WT2h, WT2l, nullptr, nullptr, T2, 256, 512, 2);
    // H2 = relu(agg(T2) + b2) -> bf16 [MPAD,256]
    k_aggb<256, true><<<aggBlocks, 256, 0, stream>>>(T2, H2, dinv, offs, deg, epk, b2, NN, MPAD);
    // T3 = H2 @ W3 -> bf16 [MPAD,128]
    k_gemm<false, 1><<<mB * 1, 256, 0, stream>>>(H2, WT3h, WT3l, nullptr, nullptr, T3, 128, 256, 1);
    // H3 = relu(agg(T3) + b3) -> bf16 [MPAD,128]
    k_aggb<128, true><<<aggBlocks, 256, 0, stream>>>(T3, H3, dinv, offs, deg, epk, b3, NN, MPAD);
    // P4 = agg(H3) -> bf16 [MPAD,128]
    k_aggb<128, false><<<aggBlocks, 256, 0, stream>>>(H3, P4, dinv, offs, deg, epk, nullptr, NN, MPAD);
    // H4 = relu(P4 @ W4 + b4) -> f32 [MPAD,200]
    k_gemm<true, 0><<<mB * 2, 256, 0, stream>>>(P4, WT4h, WT4l, b4, H4, nullptr, 200, 128, 2);

    k_reduce<<<(NN + 255) / 256, 256, 0, stream>>>(H4, gid, gsum, NN);
    k_final<<<4, 256, 0, stream>>>(gsum, gcnt, out);
}

// Round 9
// 554.408 us; speedup vs baseline: 1.5679x; 1.0822x over previous
//
#include <hip/hip_runtime.h>
#include <stdint.h>

typedef __attribute__((ext_vector_type(8))) short bf16x8;
typedef __attribute__((ext_vector_type(4))) float f32x4;

__device__ __forceinline__ float bf2f(ushort h) {
    union { uint u; float f; } v; v.u = ((uint)h) << 16; return v.f;
}
__device__ __forceinline__ ushort f2bf(float f) {
    union { float f; uint u; } v; v.f = f;
    uint u = v.u;
    return (ushort)((u + 0x7fffu + ((u >> 16) & 1u)) >> 16);
}

// async global->LDS, 16B per lane; LDS dest = wave-uniform base + lane*16
__device__ __forceinline__ void gll(const ushort* g, ushort* l) {
    __builtin_amdgcn_global_load_lds(
        (const __attribute__((address_space(1))) void*)g,
        (__attribute__((address_space(3))) void*)l, 16, 0, 0);
}

template <int VEC>
__device__ __forceinline__ void ldbf(const ushort* p, float* v) {
    if constexpr (VEC == 2) {
        uint u = *(const uint*)p;
        v[0] = bf2f((ushort)(u & 0xffffu));
        v[1] = bf2f((ushort)(u >> 16));
    } else {
        uint2 u = *(const uint2*)p;
        v[0] = bf2f((ushort)(u.x & 0xffffu));
        v[1] = bf2f((ushort)(u.x >> 16));
        v[2] = bf2f((ushort)(u.y & 0xffffu));
        v[3] = bf2f((ushort)(u.y >> 16));
    }
}

// ---------------- graph prep ----------------

// Fused: classify node (bit-exact prototype match, wave-wide __all) + convert
// x row to bf16 (128 cols, zero-padded). One wave per node.
__global__ void k_prep(const uint* __restrict__ xu, const uint* __restrict__ nfu,
                       ushort* __restrict__ xb, int* __restrict__ gid, int NN) {
    int wid = (int)((blockIdx.x * blockDim.x + threadIdx.x) >> 6);
    int lane = threadIdx.x & 63;
    if (wid >= NN) return;
    int c0 = lane * 2;
    uint w = 0u;
    int m0 = 1, m1 = 1, m2 = 1;
    if (c0 < 100) {
        uint2 xv = *(const uint2*)&xu[(size_t)wid * 100 + c0];
        uint2 a = *(const uint2*)&nfu[c0];
        uint2 b = *(const uint2*)&nfu[100 + c0];
        uint2 c = *(const uint2*)&nfu[200 + c0];
        m0 = (xv.x == a.x) & (xv.y == a.y);
        m1 = (xv.x == b.x) & (xv.y == b.y);
        m2 = (xv.x == c.x) & (xv.y == c.y);
        w = (uint)f2bf(__uint_as_float(xv.x)) | ((uint)f2bf(__uint_as_float(xv.y)) << 16);
    }
    int e0 = __all(m0), e1 = __all(m1), e2 = __all(m2);
    *(uint*)&xb[(size_t)wid * 128 + c0] = w;
    if (lane == 0) {
        int g = e0 ? 0 : (e1 ? 3 : (e2 ? 1 : 2));
        gid[wid] = g;
    }
}

__global__ void k_deg(const int* __restrict__ dst, int E, int* __restrict__ deg) {
    int e = blockIdx.x * blockDim.x + threadIdx.x;
    if (e < E) atomicAdd(&deg[dst[e]], 1);
}

__global__ void k_dinv(const int* __restrict__ deg, float* __restrict__ dinv, int NN) {
    int i = blockIdx.x * blockDim.x + threadIdx.x;
    if (i < NN) dinv[i] = 1.0f / sqrtf((float)(deg[i] + 1));  // +1 self loop
}

// 3-phase parallel exclusive scan of deg -> offs
__global__ void k_scanA(const int* __restrict__ deg, int* __restrict__ offs,
                        int* __restrict__ bsum, int NN) {
    __shared__ int lds[256];
    int t = threadIdx.x;
    int i = blockIdx.x * 256 + t;
    int v = (i < NN) ? deg[i] : 0;
    lds[t] = v;
    __syncthreads();
    for (int d = 1; d < 256; d <<= 1) {
        int u = (t >= d) ? lds[t - d] : 0;
        __syncthreads();
        lds[t] += u;
        __syncthreads();
    }
    if (i < NN) offs[i] = lds[t] - v;  // block-local exclusive
    if (t == 255) bsum[blockIdx.x] = lds[255];
}

__global__ void k_scanB(int* __restrict__ bsum, int nb) {
    __shared__ int lds[256];
    int t = threadIdx.x;
    int v = (t < nb) ? bsum[t] : 0;
    lds[t] = v;
    __syncthreads();
    for (int d = 1; d < 256; d <<= 1) {
        int u = (t >= d) ? lds[t - d] : 0;
        __syncthreads();
        lds[t] += u;
        __syncthreads();
    }
    if (t < nb) bsum[t] = lds[t] - v;  // exclusive block prefix
}

__global__ void k_scanC(int* __restrict__ offs, const int* __restrict__ bsum, int NN) {
    int i = blockIdx.x * 256 + threadIdx.x;
    if (i < NN) offs[i] += bsum[blockIdx.x];
}

__global__ void k_fill(const int* __restrict__ src, const int* __restrict__ dst, int E,
                       const float* __restrict__ dinv, const int* __restrict__ offs,
                       int* __restrict__ cur, uint2* __restrict__ epk) {
    int e = blockIdx.x * blockDim.x + threadIdx.x;
    if (e >= E) return;
    int s = src[e], d = dst[e];
    int p = offs[d] + atomicAdd(&cur[d], 1);
    epk[p] = make_uint2((uint)s, __float_as_uint(dinv[s] * dinv[d]));
}

// ---------------- aggregation over bf16 rows (gather, wave per node) ----------------

template <int D, bool BR>
__global__ void k_aggb(const ushort* __restrict__ H, ushort* __restrict__ outb,
                       const float* __restrict__ dinv, const int* __restrict__ offs,
                       const int* __restrict__ deg, const uint2* __restrict__ epk,
                       const float* __restrict__ bias, int NN, int NNpad) {
    constexpr int VEC = D / 64;
    int wid = (int)((blockIdx.x * blockDim.x + threadIdx.x) >> 6);
    int lane = threadIdx.x & 63;
    if (wid >= NNpad) return;
    int c0 = lane * VEC;
    ushort* op = outb + (size_t)wid * D + c0;
    if (wid >= NN) {  // zero pad rows
        if (VEC == 2) *(uint*)op = 0u;
        else *(uint2*)op = make_uint2(0u, 0u);
        return;
    }
    float acc[VEC], t0[VEC], t1[VEC];
    float di = dinv[wid];
    float sw = di * di;
    ldbf<VEC>(H + (size_t)wid * D + c0, t0);
#pragma unroll
    for (int j = 0; j < VEC; ++j) acc[j] = sw * t0[j];
    int e = offs[wid];
    int end = e + deg[wid];
    for (; e + 1 < end; e += 2) {
        uint2 q0 = epk[e], q1 = epk[e + 1];
        ldbf<VEC>(H + (size_t)q0.x * D + c0, t0);
        ldbf<VEC>(H + (size_t)q1.x * D + c0, t1);
        float w0 = __uint_as_float(q0.y), w1 = __uint_as_float(q1.y);
#pragma unroll
        for (int j = 0; j < VEC; ++j) acc[j] += w0 * t0[j];
#pragma unroll
        for (int j = 0; j < VEC; ++j) acc[j] += w1 * t1[j];
    }
    if (e < end) {
        uint2 q0 = epk[e];
        ldbf<VEC>(H + (size_t)q0.x * D + c0, t0);
        float w0 = __uint_as_float(q0.y);
#pragma unroll
        for (int j = 0; j < VEC; ++j) acc[j] += w0 * t0[j];
    }
    ushort r[VEC];
#pragma unroll
    for (int j = 0; j < VEC; ++j) {
        float v = acc[j];
        if (BR) v = fmaxf(v + bias[c0 + j], 0.0f);
        r[j] = f2bf(v);
    }
    if (VEC == 2) {
        *(uint*)op = (uint)r[0] | ((uint)r[1] << 16);
    } else {
        uint2 w;
        w.x = (uint)r[0] | ((uint)r[1] << 16);
        w.y = (uint)r[2] | ((uint)r[3] << 16);
        *(uint2*)op = w;
    }
}

// ---------------- MFMA GEMM: A bf16 single plane, W hi/lo split (2-term) ----------------
// Block tile 128x128, 4 waves (64x64). OUT: 0 = f32, 1 = bf16,
// 2 = fused per-group row reduction into gsum[4][Nc] (no C store).

template <bool BR, int OUT>
__global__ __launch_bounds__(256) void k_gemm(
        const ushort* __restrict__ A,
        const ushort* __restrict__ Bh, const ushort* __restrict__ Bl,
        const float* __restrict__ bias,
        float* __restrict__ Cf, ushort* __restrict__ Cb,
        int Nc, int K, int tNb,
        const int* __restrict__ gid, float* __restrict__ gsum, int NN) {
    __shared__ union {
        ushort st[3][128 * 32];
        float epi[64 * 132];
    } sm;
    __shared__ int gcode[64];
    int bm = blockIdx.x / tNb, bn = blockIdx.x % tNb;
    int m0 = bm * 128, n0 = bn * 128;
    int wv = threadIdx.x >> 6, lane = threadIdx.x & 63;
    int l15 = lane & 15, quad = lane >> 4;
    const ushort* gsrc;
    ushort* ldst;
    int ng;
    if (wv == 0)      { gsrc = A  + (size_t)m0 * K;        ldst = sm.st[0];        ng = 4; }
    else if (wv == 1) { gsrc = A  + (size_t)(m0 + 64) * K; ldst = sm.st[0] + 2048; ng = 4; }
    else if (wv == 2) { gsrc = Bh + (size_t)n0 * K;        ldst = sm.st[1];        ng = 8; }
    else              { gsrc = Bl + (size_t)n0 * K;        ldst = sm.st[2];        ng = 8; }
    const ushort* gBase = gsrc + (size_t)(lane >> 2) * K + (lane & 3) * 8;
    int wm = (wv >> 1) * 64, wn = (wv & 1) * 64;
    const ushort* sA_ = sm.st[0];
    const ushort* sBh_ = sm.st[1];
    const ushort* sBl_ = sm.st[2];
    f32x4 acc[4][4] = {};
    for (int k0 = 0; k0 < K; k0 += 32) {
        for (int i = 0; i < ng; ++i)
            gll(gBase + (size_t)(16 * i) * K + k0, ldst + i * 512);
        __syncthreads();
        bf16x8 Af[4], Bfh[4], Bfl[4];
#pragma unroll
        for (int i = 0; i < 4; ++i) {
            int ra = (wm + 16 * i + l15) * 32 + quad * 8;
            int rb = (wn + 16 * i + l15) * 32 + quad * 8;
            Af[i]  = *(const bf16x8*)(sA_ + ra);
            Bfh[i] = *(const bf16x8*)(sBh_ + rb);
            Bfl[i] = *(const bf16x8*)(sBl_ + rb);
        }
#pragma unroll
        for (int mi = 0; mi < 4; ++mi)
#pragma unroll
            for (int ni = 0; ni < 4; ++ni) {
                acc[mi][ni] = __builtin_amdgcn_mfma_f32_16x16x32_bf16(Af[mi], Bfh[ni], acc[mi][ni], 0, 0, 0);
                acc[mi][ni] = __builtin_amdgcn_mfma_f32_16x16x32_bf16(Af[mi], Bfl[ni], acc[mi][ni], 0, 0, 0);
            }
        __syncthreads();
    }
    float bia[4] = {0.f, 0.f, 0.f, 0.f};
    if (BR) {
#pragma unroll
        for (int ni = 0; ni < 4; ++ni) {
            int col = n0 + wn + 16 * ni + l15;
            if (col < Nc) bia[ni] = bias[col];
        }
    }
    float* epi = sm.epi;
    int t = threadIdx.x;
    float s0 = 0.f, s1 = 0.f, s2 = 0.f, s3 = 0.f;  // OUT==2 per-group sums
    int colR = t & 127, rg = t >> 7;
    for (int half = 0; half < 2; ++half) {
        if ((wv >> 1) == half) {
#pragma unroll
            for (int mi = 0; mi < 4; ++mi)
#pragma unroll
                for (int r = 0; r < 4; ++r) {
                    int rl = mi * 16 + quad * 4 + r;
#pragma unroll
                    for (int ni = 0; ni < 4; ++ni) {
                        float v = acc[mi][ni][r];
                        if (BR) v = fmaxf(v + bia[ni], 0.0f);
                        epi[rl * 132 + wn + ni * 16 + l15] = v;
                    }
                }
        }
        if (OUT == 2 && t < 64) {
            int grow = m0 + half * 64 + t;
            gcode[t] = (grow < NN) ? gid[grow] : -1;
        }
        __syncthreads();
        if (OUT == 2) {
#pragma unroll 4
            for (int r = 0; r < 32; ++r) {
                int row = rg * 32 + r;
                int g = gcode[row];
                float v = epi[row * 132 + colR];
                s0 += (g == 0) ? v : 0.f;
                s1 += (g == 1) ? v : 0.f;
                s2 += (g == 2) ? v : 0.f;
                s3 += (g == 3) ? v : 0.f;
            }
        } else {
#pragma unroll
            for (int j = 0; j < 16; ++j) {
                int e = (j * 256 + t) * 2;
                int rl = e >> 7, cl = e & 127;
                int grow = m0 + half * 64 + rl;
                int gcol = n0 + cl;
                float v0 = epi[rl * 132 + cl];
                float v1 = epi[rl * 132 + cl + 1];
                if (OUT == 0) {
                    if (gcol < Nc) {
                        float2 w; w.x = v0; w.y = v1;
                        *(float2*)&Cf[(size_t)grow * Nc + gcol] = w;
                    }
                } else {
                    *(uint*)&Cb[(size_t)grow * Nc + gcol] = (uint)f2bf(v0) | ((uint)f2bf(v1) << 16);
                }
            }
        }
        __syncthreads();
    }
    if (OUT == 2) {
        if (rg == 1) {
            epi[colR * 4 + 0] = s0; epi[colR * 4 + 1] = s1;
            epi[colR * 4 + 2] = s2; epi[colR * 4 + 3] = s3;
        }
        __syncthreads();
        if (rg == 0) {
            s0 += epi[colR * 4 + 0]; s1 += epi[colR * 4 + 1];
            s2 += epi[colR * 4 + 2]; s3 += epi[colR * 4 + 3];
            int gcol = n0 + colR;
            if (gcol < Nc) {
                atomicAdd(&gsum[0 * Nc + gcol], s0);
                atomicAdd(&gsum[1 * Nc + gcol], s1);
                atomicAdd(&gsum[2 * Nc + gcol], s2);
                atomicAdd(&gsum[3 * Nc + gcol], s3);
            }
        }
    }
}

// ---------------- weight transpose + split ----------------

__global__ void k_tr2(const float* __restrict__ W, ushort* __restrict__ WTh, ushort* __restrict__ WTl,
                      int K, int Nc, int KP, int NP) {
    int idx = blockIdx.x * blockDim.x + threadIdx.x;
    if (idx >= NP * KP) return;
    int n = idx / KP, k = idx % KP;
    float w = (n < Nc && k < K) ? W[(size_t)k * Nc + n] : 0.0f;
    ushort hi = f2bf(w);
    ushort lo = f2bf(w - bf2f(hi));
    WTh[idx] = hi;
    WTl[idx] = lo;
}

// ---------------- final: count groups + divide ----------------

__global__ void k_final(const float* __restrict__ gsum, const int* __restrict__ gid,
                        int NN, float* __restrict__ out) {
    __shared__ int cnt[4];
    int t = threadIdx.x;  // 1024
    if (t < 4) cnt[t] = 0;
    __syncthreads();
    int c0 = 0, c1 = 0, c2 = 0, c3 = 0;
    for (int i = t; i < NN; i += 1024) {
        int g = gid[i];
        c0 += (g == 0); c1 += (g == 1); c2 += (g == 2); c3 += (g == 3);
    }
    if (c0) atomicAdd(&cnt[0], c0);
    if (c1) atomicAdd(&cnt[1], c1);
    if (c2) atomicAdd(&cnt[2], c2);
    if (c3) atomicAdd(&cnt[3], c3);
    __syncthreads();
    if (t < 800) {
        int g = t / 200;
        int c = cnt[g];
        out[t] = (c > 0) ? gsum[t] / (float)c : 0.0f;
    }
}

// ---------------- launch ----------------

extern "C" void kernel_launch(void* const* d_in, const int* in_sizes, int n_in,
                              void* d_out, int out_size, void* d_ws, size_t ws_size,
                              hipStream_t stream) {
    const float* x  = (const float*)d_in[0];
    const float* nf = (const float*)d_in[1];
    const int* ei   = (const int*)d_in[2];
    const float* W1 = (const float*)d_in[3];
    const float* b1 = (const float*)d_in[4];
    const float* W2 = (const float*)d_in[5];
    const float* b2 = (const float*)d_in[6];
    const float* W3 = (const float*)d_in[7];
    const float* b3 = (const float*)d_in[8];
    const float* W4 = (const float*)d_in[9];
    const float* b4 = (const float*)d_in[10];
    float* out = (float*)d_out;

    const int NN = in_sizes[0] / 100;  // 50000
    const int E  = in_sizes[2] / 2;    // 800000
    const int MPAD = ((NN + 127) / 128) * 128;  // 50048
    const int NB = (NN + 255) / 256;   // scan blocks (196 <= 256)
    const int* src = ei;
    const int* dst = ei + E;

    char* p = (char*)d_ws;
    auto alloc = [&](size_t bytes) -> char* {
        char* r = p;
        p += (bytes + 255) & ~(size_t)255;
        return r;
    };
    char* zz = p;
    int*   deg  = (int*)alloc((size_t)NN * 4);
    int*   cur  = (int*)alloc((size_t)NN * 4);
    float* gsum = (float*)alloc(800 * 4);
    size_t zz_bytes = (size_t)(p - zz);
    float* dinv = (float*)alloc((size_t)NN * 4);
    int*   offs = (int*)alloc((size_t)NN * 4);
    int*   bsum = (int*)alloc(1024);
    int*   gid  = (int*)alloc((size_t)NN * 4);
    uint2* epk  = (uint2*)alloc((size_t)E * 8);
    ushort* WT1h = (ushort*)alloc((size_t)512 * 128 * 2);
    ushort* WT1l = (ushort*)alloc((size_t)512 * 128 * 2);
    ushort* WT2h = (ushort*)alloc((size_t)256 * 512 * 2);
    ushort* WT2l = (ushort*)alloc((size_t)256 * 512 * 2);
    ushort* WT3h = (ushort*)alloc((size_t)128 * 256 * 2);
    ushort* WT3l = (ushort*)alloc((size_t)128 * 256 * 2);
    ushort* WT4h = (ushort*)alloc((size_t)256 * 128 * 2);
    ushort* WT4l = (ushort*)alloc((size_t)256 * 128 * 2);
    ushort* xb = (ushort*)alloc((size_t)NN * 128 * 2);
    ushort* P1 = (ushort*)alloc((size_t)MPAD * 128 * 2);
    ushort* H1 = (ushort*)alloc((size_t)MPAD * 512 * 2);
    ushort* T2 = (ushort*)alloc((size_t)MPAD * 256 * 2);
    ushort* H2 = (ushort*)alloc((size_t)MPAD * 256 * 2);
    ushort* T3 = (ushort*)alloc((size_t)MPAD * 128 * 2);
    ushort* H3 = (ushort*)alloc((size_t)MPAD * 128 * 2);
    ushort* P4 = (ushort*)alloc((size_t)MPAD * 128 * 2);

    hipMemsetAsync(zz, 0, zz_bytes, stream);

    k_prep<<<(NN + 3) / 4, 256, 0, stream>>>((const uint*)x, (const uint*)nf, xb, gid, NN);
    k_deg<<<(E + 255) / 256, 256, 0, stream>>>(dst, E, deg);
    k_dinv<<<(NN + 255) / 256, 256, 0, stream>>>(deg, dinv, NN);
    k_scanA<<<NB, 256, 0, stream>>>(deg, offs, bsum, NN);
    k_scanB<<<1, 256, 0, stream>>>(bsum, NB);
    k_scanC<<<NB, 256, 0, stream>>>(offs, bsum, NN);
    k_fill<<<(E + 255) / 256, 256, 0, stream>>>(src, dst, E, dinv, offs, cur, epk);

    k_tr2<<<(512 * 128 + 255) / 256, 256, 0, stream>>>(W1, WT1h, WT1l, 100, 512, 128, 512);
    k_tr2<<<(256 * 512 + 255) / 256, 256, 0, stream>>>(W2, WT2h, WT2l, 512, 256, 512, 256);
    k_tr2<<<(128 * 256 + 255) / 256, 256, 0, stream>>>(W3, WT3h, WT3l, 256, 128, 256, 128);
    k_tr2<<<(256 * 128 + 255) / 256, 256, 0, stream>>>(W4, WT4h, WT4l, 128, 200, 128, 256);

    int aggBlocks = MPAD / 4;  // one wave per node incl. pad rows
    int mB = MPAD / 128;

    // P1 = agg(xb) -> bf16 [MPAD,128]
    k_aggb<128, false><<<aggBlocks, 256, 0, stream>>>(xb, P1, dinv, offs, deg, epk, nullptr, NN, MPAD);
    // H1 = relu(P1 @ W1 + b1) -> bf16 [MPAD,512]
    k_gemm<true, 1><<<mB * 4, 256, 0, stream>>>(P1, WT1h, WT1l, b1, nullptr, H1, 512, 128, 4, nullptr, nullptr, 0);
    // T2 = H1 @ W2 -> bf16 [MPAD,256]
    k_gemm<false, 1><<<mB * 2, 256, 0, stream>>>(H1, WT2h, WT2l, nullptr, nullptr, T2, 256, 512, 2, nullptr, nullptr, 0);
    // H2 = relu(agg(T2) + b2) -> bf16 [MPAD,256]
    k_aggb<256, true><<<aggBlocks, 256, 0, stream>>>(T2, H2, dinv, offs, deg, epk, b2, NN, MPAD);
    // T3 = H2 @ W3 -> bf16 [MPAD,128]
    k_gemm<false, 1><<<mB * 1, 256, 0, stream>>>(H2, WT3h, WT3l, nullptr, nullptr, T3, 128, 256, 1, nullptr, nullptr, 0);
    // H3 = relu(agg(T3) + b3) -> bf16 [MPAD,128]
    k_aggb<128, true><<<aggBlocks, 256, 0, stream>>>(T3, H3, dinv, offs, deg, epk, b3, NN, MPAD);
    // P4 = agg(H3) -> bf16 [MPAD,128]
    k_aggb<128, false><<<aggBlocks, 256, 0, stream>>>(H3, P4, dinv, offs, deg, epk, nullptr, NN, MPAD);
    // relu(P4 @ W4 + b4) reduced per-group directly into gsum (no H4 tensor)
    k_gemm<true, 2><<<mB * 2, 256, 0, stream>>>(P4, WT4h, WT4l, b4, nullptr, nullptr, 200, 128, 2, gid, gsum, NN);

    k_final<<<1, 1024, 0, stream>>>(gsum, gid, NN, out);
}

// Round 10
// 535.569 us; speedup vs baseline: 1.6230x; 1.0352x over previous
//
#include <hip/hip_runtime.h>
#include <stdint.h>

typedef __attribute__((ext_vector_type(8))) short bf16x8;
typedef __attribute__((ext_vector_type(4))) float f32x4;

__device__ __forceinline__ float bf2f(ushort h) {
    union { uint u; float f; } v; v.u = ((uint)h) << 16; return v.f;
}
__device__ __forceinline__ ushort f2bf(float f) {
    union { float f; uint u; } v; v.f = f;
    uint u = v.u;
    return (ushort)((u + 0x7fffu + ((u >> 16) & 1u)) >> 16);
}

// async global->LDS, 16B per lane; LDS dest = wave-uniform base + lane*16
__device__ __forceinline__ void gll(const ushort* g, ushort* l) {
    __builtin_amdgcn_global_load_lds(
        (const __attribute__((address_space(1))) void*)g,
        (__attribute__((address_space(3))) void*)l, 16, 0, 0);
}

template <int VEC>
__device__ __forceinline__ void ldbf(const ushort* p, float* v) {
    if constexpr (VEC == 4) {
        uint2 u = *(const uint2*)p;
        v[0] = bf2f((ushort)(u.x & 0xffffu));
        v[1] = bf2f((ushort)(u.x >> 16));
        v[2] = bf2f((ushort)(u.y & 0xffffu));
        v[3] = bf2f((ushort)(u.y >> 16));
    } else {  // VEC == 8
        uint4 u = *(const uint4*)p;
        v[0] = bf2f((ushort)(u.x & 0xffffu));
        v[1] = bf2f((ushort)(u.x >> 16));
        v[2] = bf2f((ushort)(u.y & 0xffffu));
        v[3] = bf2f((ushort)(u.y >> 16));
        v[4] = bf2f((ushort)(u.z & 0xffffu));
        v[5] = bf2f((ushort)(u.z >> 16));
        v[6] = bf2f((ushort)(u.w & 0xffffu));
        v[7] = bf2f((ushort)(u.w >> 16));
    }
}

// ---------------- merged init: prep (classify + x->bf16) | deg | weight split ----------------

__device__ __forceinline__ void tr2_one(const float* __restrict__ W,
                                        ushort* __restrict__ WTh, ushort* __restrict__ WTl,
                                        int K, int Nc, int KP, int idx) {
    int n = idx / KP, k = idx % KP;
    float w = (n < Nc && k < K) ? W[(size_t)k * Nc + n] : 0.0f;
    ushort hi = f2bf(w);
    ushort lo = f2bf(w - bf2f(hi));
    WTh[idx] = hi;
    WTl[idx] = lo;
}

__global__ void k_init(const uint* __restrict__ xu, const uint* __restrict__ nfu,
                       ushort* __restrict__ xb, int* __restrict__ gid, int NN,
                       const int* __restrict__ dst, int E, int* __restrict__ deg,
                       const float* __restrict__ W1, const float* __restrict__ W2,
                       const float* __restrict__ W3, const float* __restrict__ W4,
                       ushort* __restrict__ WT1h, ushort* __restrict__ WT1l,
                       ushort* __restrict__ WT2h, ushort* __restrict__ WT2l,
                       ushort* __restrict__ WT3h, ushort* __restrict__ WT3l,
                       ushort* __restrict__ WT4h, ushort* __restrict__ WT4l,
                       int PB, int EB) {
    int b = blockIdx.x;
    if (b < PB) {
        int wid = b * 4 + (threadIdx.x >> 6);
        int lane = threadIdx.x & 63;
        if (wid >= NN) return;
        int c0 = lane * 2;
        uint w = 0u;
        int m0 = 1, m1 = 1, m2 = 1;
        if (c0 < 100) {
            uint2 xv = *(const uint2*)&xu[(size_t)wid * 100 + c0];
            uint2 a = *(const uint2*)&nfu[c0];
            uint2 bb = *(const uint2*)&nfu[100 + c0];
            uint2 c = *(const uint2*)&nfu[200 + c0];
            m0 = (xv.x == a.x) & (xv.y == a.y);
            m1 = (xv.x == bb.x) & (xv.y == bb.y);
            m2 = (xv.x == c.x) & (xv.y == c.y);
            w = (uint)f2bf(__uint_as_float(xv.x)) | ((uint)f2bf(__uint_as_float(xv.y)) << 16);
        }
        int e0 = __all(m0), e1 = __all(m1), e2 = __all(m2);
        *(uint*)&xb[(size_t)wid * 128 + c0] = w;
        if (lane == 0) gid[wid] = e0 ? 0 : (e1 ? 3 : (e2 ? 1 : 2));
    } else if (b < PB + EB) {
        int e = (b - PB) * 256 + threadIdx.x;
        if (e < E) atomicAdd(&deg[dst[e]], 1);
    } else {
        int idx = (b - PB - EB) * 256 + threadIdx.x;
        if (idx < 65536) tr2_one(W1, WT1h, WT1l, 100, 512, 128, idx);
        else if (idx < 196608) tr2_one(W2, WT2h, WT2l, 512, 256, 512, idx - 65536);
        else if (idx < 229376) tr2_one(W3, WT3h, WT3l, 256, 128, 256, idx - 196608);
        else if (idx < 262144) tr2_one(W4, WT4h, WT4l, 128, 200, 128, idx - 229376);
    }
}

// ---------------- 3-phase parallel exclusive scan (A also computes dinv) ----------------

__global__ void k_scanA(const int* __restrict__ deg, int* __restrict__ offs,
                        int* __restrict__ bsum, float* __restrict__ dinv, int NN) {
    __shared__ int lds[256];
    int t = threadIdx.x;
    int i = blockIdx.x * 256 + t;
    int v = (i < NN) ? deg[i] : 0;
    if (i < NN) dinv[i] = 1.0f / sqrtf((float)(v + 1));  // +1 self loop
    lds[t] = v;
    __syncthreads();
    for (int d = 1; d < 256; d <<= 1) {
        int u = (t >= d) ? lds[t - d] : 0;
        __syncthreads();
        lds[t] += u;
        __syncthreads();
    }
    if (i < NN) offs[i] = lds[t] - v;  // block-local exclusive
    if (t == 255) bsum[blockIdx.x] = lds[255];
}

__global__ void k_scanB(int* __restrict__ bsum, int nb) {
    __shared__ int lds[256];
    int t = threadIdx.x;
    int v = (t < nb) ? bsum[t] : 0;
    lds[t] = v;
    __syncthreads();
    for (int d = 1; d < 256; d <<= 1) {
        int u = (t >= d) ? lds[t - d] : 0;
        __syncthreads();
        lds[t] += u;
        __syncthreads();
    }
    if (t < nb) bsum[t] = lds[t] - v;  // exclusive block prefix
}

__global__ void k_scanC(int* __restrict__ offs, const int* __restrict__ bsum, int NN) {
    int i = blockIdx.x * 256 + threadIdx.x;
    if (i < NN) offs[i] += bsum[blockIdx.x];
}

__global__ void k_fill(const int* __restrict__ src, const int* __restrict__ dst, int E,
                       const float* __restrict__ dinv, const int* __restrict__ offs,
                       int* __restrict__ cur, uint2* __restrict__ epk) {
    int e = blockIdx.x * blockDim.x + threadIdx.x;
    if (e >= E) return;
    int s = src[e], d = dst[e];
    int p = offs[d] + atomicAdd(&cur[d], 1);
    epk[p] = make_uint2((uint)s, __float_as_uint(dinv[s] * dinv[d]));
}

// ---------------- aggregation: 2 nodes per wave (half-wave per node) ----------------
// bf16 in/out, f32 accumulate. Lanes 0-31 -> node wid0, 32-63 -> node wid0+1.

template <int D, bool BR>
__global__ void k_agg2(const ushort* __restrict__ H, ushort* __restrict__ outb,
                       const float* __restrict__ dinv, const int* __restrict__ offs,
                       const int* __restrict__ deg, const uint2* __restrict__ epk,
                       const float* __restrict__ bias, int NN, int NNpad) {
    constexpr int VEC = D / 32;
    int wv = threadIdx.x >> 6, lane = threadIdx.x & 63;
    int half = lane >> 5, sl = lane & 31;
    int wid = blockIdx.x * 8 + wv * 2 + half;
    int c0 = sl * VEC;
    bool live = (wid < NN);
    float acc[VEC];
#pragma unroll
    for (int j = 0; j < VEC; ++j) acc[j] = 0.0f;
    int beg = 0, dg = 0;
    if (live) {
        float t0[VEC];
        ldbf<VEC>(H + (size_t)wid * D + c0, t0);
        float di = dinv[wid];
        float sw = di * di;
#pragma unroll
        for (int j = 0; j < VEC; ++j) acc[j] = sw * t0[j];
        beg = offs[wid];
        dg = deg[wid];
    }
    int mx = max(dg, __shfl_xor(dg, 32));
    int end = beg + dg;
    for (int it = 0; it < mx; it += 2) {
        int e = beg + it;
        if (e < end) {
            uint2 q0 = epk[e];
            float t0[VEC];
            ldbf<VEC>(H + (size_t)q0.x * D + c0, t0);
            float w0 = __uint_as_float(q0.y);
            if (e + 1 < end) {
                uint2 q1 = epk[e + 1];
                float t1[VEC];
                ldbf<VEC>(H + (size_t)q1.x * D + c0, t1);
                float w1 = __uint_as_float(q1.y);
#pragma unroll
                for (int j = 0; j < VEC; ++j) acc[j] += w1 * t1[j];
            }
#pragma unroll
            for (int j = 0; j < VEC; ++j) acc[j] += w0 * t0[j];
        }
    }
    if (wid >= NNpad) return;
    ushort r[VEC];
#pragma unroll
    for (int j = 0; j < VEC; ++j) {
        float v = acc[j];
        if (BR && live) v = fmaxf(v + bias[c0 + j], 0.0f);
        r[j] = f2bf(v);
    }
    ushort* op = outb + (size_t)wid * D + c0;
    if (VEC == 4) {
        uint2 w;
        w.x = (uint)r[0] | ((uint)r[1] << 16);
        w.y = (uint)r[2] | ((uint)r[3] << 16);
        *(uint2*)op = w;
    } else {
        uint4 w;
        w.x = (uint)r[0] | ((uint)r[1] << 16);
        w.y = (uint)r[2] | ((uint)r[3] << 16);
        w.z = (uint)r[4] | ((uint)r[5] << 16);
        w.w = (uint)r[6] | ((uint)r[7] << 16);
        *(uint4*)op = w;
    }
}

// ---------------- MFMA GEMM: A bf16 single plane, W hi/lo split (2-term) ----------------
// Block tile 128x128, 4 waves (64x64). OUT: 1 = bf16 store,
// 2 = fused per-group row reduction into gsum[4][Nc] (no C store).

template <bool BR, int OUT>
__global__ __launch_bounds__(256) void k_gemm(
        const ushort* __restrict__ A,
        const ushort* __restrict__ Bh, const ushort* __restrict__ Bl,
        const float* __restrict__ bias,
        ushort* __restrict__ Cb,
        int Nc, int K, int tNb,
        const int* __restrict__ gid, float* __restrict__ gsum, int NN) {
    __shared__ union {
        ushort st[3][128 * 32];
        float epi[64 * 132];
    } sm;
    __shared__ int gcode[64];
    int bm = blockIdx.x / tNb, bn = blockIdx.x % tNb;
    int m0 = bm * 128, n0 = bn * 128;
    int wv = threadIdx.x >> 6, lane = threadIdx.x & 63;
    int l15 = lane & 15, quad = lane >> 4;
    const ushort* gsrc;
    ushort* ldst;
    int ng;
    if (wv == 0)      { gsrc = A  + (size_t)m0 * K;        ldst = sm.st[0];        ng = 4; }
    else if (wv == 1) { gsrc = A  + (size_t)(m0 + 64) * K; ldst = sm.st[0] + 2048; ng = 4; }
    else if (wv == 2) { gsrc = Bh + (size_t)n0 * K;        ldst = sm.st[1];        ng = 8; }
    else              { gsrc = Bl + (size_t)n0 * K;        ldst = sm.st[2];        ng = 8; }
    const ushort* gBase = gsrc + (size_t)(lane >> 2) * K + (lane & 3) * 8;
    int wm = (wv >> 1) * 64, wn = (wv & 1) * 64;
    const ushort* sA_ = sm.st[0];
    const ushort* sBh_ = sm.st[1];
    const ushort* sBl_ = sm.st[2];
    f32x4 acc[4][4] = {};
    for (int k0 = 0; k0 < K; k0 += 32) {
        for (int i = 0; i < ng; ++i)
            gll(gBase + (size_t)(16 * i) * K + k0, ldst + i * 512);
        __syncthreads();
        bf16x8 Af[4], Bfh[4], Bfl[4];
#pragma unroll
        for (int i = 0; i < 4; ++i) {
            int ra = (wm + 16 * i + l15) * 32 + quad * 8;
            int rb = (wn + 16 * i + l15) * 32 + quad * 8;
            Af[i]  = *(const bf16x8*)(sA_ + ra);
            Bfh[i] = *(const bf16x8*)(sBh_ + rb);
            Bfl[i] = *(const bf16x8*)(sBl_ + rb);
        }
#pragma unroll
        for (int mi = 0; mi < 4; ++mi)
#pragma unroll
            for (int ni = 0; ni < 4; ++ni) {
                acc[mi][ni] = __builtin_amdgcn_mfma_f32_16x16x32_bf16(Af[mi], Bfh[ni], acc[mi][ni], 0, 0, 0);
                acc[mi][ni] = __builtin_amdgcn_mfma_f32_16x16x32_bf16(Af[mi], Bfl[ni], acc[mi][ni], 0, 0, 0);
            }
        __syncthreads();
    }
    float bia[4] = {0.f, 0.f, 0.f, 0.f};
    if (BR) {
#pragma unroll
        for (int ni = 0; ni < 4; ++ni) {
            int col = n0 + wn + 16 * ni + l15;
            if (col < Nc) bia[ni] = bias[col];
        }
    }
    float* epi = sm.epi;
    int t = threadIdx.x;
    float s0 = 0.f, s1 = 0.f, s2 = 0.f, s3 = 0.f;  // OUT==2 per-group sums
    int colR = t & 127, rg = t >> 7;
    for (int half = 0; half < 2; ++half) {
        if ((wv >> 1) == half) {
#pragma unroll
            for (int mi = 0; mi < 4; ++mi)
#pragma unroll
                for (int r = 0; r < 4; ++r) {
                    int rl = mi * 16 + quad * 4 + r;
#pragma unroll
                    for (int ni = 0; ni < 4; ++ni) {
                        float v = acc[mi][ni][r];
                        if (BR) v = fmaxf(v + bia[ni], 0.0f);
                        epi[rl * 132 + wn + ni * 16 + l15] = v;
                    }
                }
        }
        if (OUT == 2 && t < 64) {
            int grow = m0 + half * 64 + t;
            gcode[t] = (grow < NN) ? gid[grow] : -1;
        }
        __syncthreads();
        if (OUT == 2) {
#pragma unroll 4
            for (int r = 0; r < 32; ++r) {
                int row = rg * 32 + r;
                int g = gcode[row];
                float v = epi[row * 132 + colR];
                s0 += (g == 0) ? v : 0.f;
                s1 += (g == 1) ? v : 0.f;
                s2 += (g == 2) ? v : 0.f;
                s3 += (g == 3) ? v : 0.f;
            }
        } else {
#pragma unroll
            for (int j = 0; j < 16; ++j) {
                int e = (j * 256 + t) * 2;
                int rl = e >> 7, cl = e & 127;
                int grow = m0 + half * 64 + rl;
                int gcol = n0 + cl;
                float v0 = epi[rl * 132 + cl];
                float v1 = epi[rl * 132 + cl + 1];
                *(uint*)&Cb[(size_t)grow * Nc + gcol] = (uint)f2bf(v0) | ((uint)f2bf(v1) << 16);
            }
        }
        __syncthreads();
    }
    if (OUT == 2) {
        if (rg == 1) {
            epi[colR * 4 + 0] = s0; epi[colR * 4 + 1] = s1;
            epi[colR * 4 + 2] = s2; epi[colR * 4 + 3] = s3;
        }
        __syncthreads();
        if (rg == 0) {
            s0 += epi[colR * 4 + 0]; s1 += epi[colR * 4 + 1];
            s2 += epi[colR * 4 + 2]; s3 += epi[colR * 4 + 3];
            int gcol = n0 + colR;
            if (gcol < Nc) {
                atomicAdd(&gsum[0 * Nc + gcol], s0);
                atomicAdd(&gsum[1 * Nc + gcol], s1);
                atomicAdd(&gsum[2 * Nc + gcol], s2);
                atomicAdd(&gsum[3 * Nc + gcol], s3);
            }
        }
    }
}

// ---------------- final: count groups + divide ----------------

__global__ void k_final(const float* __restrict__ gsum, const int* __restrict__ gid,
                        int NN, float* __restrict__ out) {
    __shared__ int cnt[4];
    int t = threadIdx.x;  // 1024
    if (t < 4) cnt[t] = 0;
    __syncthreads();
    int c0 = 0, c1 = 0, c2 = 0, c3 = 0;
    for (int i = t; i < NN; i += 1024) {
        int g = gid[i];
        c0 += (g == 0); c1 += (g == 1); c2 += (g == 2); c3 += (g == 3);
    }
    if (c0) atomicAdd(&cnt[0], c0);
    if (c1) atomicAdd(&cnt[1], c1);
    if (c2) atomicAdd(&cnt[2], c2);
    if (c3) atomicAdd(&cnt[3], c3);
    __syncthreads();
    if (t < 800) {
        int g = t / 200;
        int c = cnt[g];
        out[t] = (c > 0) ? gsum[t] / (float)c : 0.0f;
    }
}

// ---------------- launch ----------------

extern "C" void kernel_launch(void* const* d_in, const int* in_sizes, int n_in,
                              void* d_out, int out_size, void* d_ws, size_t ws_size,
                              hipStream_t stream) {
    const float* x  = (const float*)d_in[0];
    const float* nf = (const float*)d_in[1];
    const int* ei   = (const int*)d_in[2];
    const float* W1 = (const float*)d_in[3];
    const float* b1 = (const float*)d_in[4];
    const float* W2 = (const float*)d_in[5];
    const float* b2 = (const float*)d_in[6];
    const float* W3 = (const float*)d_in[7];
    const float* b3 = (const float*)d_in[8];
    const float* W4 = (const float*)d_in[9];
    const float* b4 = (const float*)d_in[10];
    float* out = (float*)d_out;

    const int NN = in_sizes[0] / 100;  // 50000
    const int E  = in_sizes[2] / 2;    // 800000
    const int MPAD = ((NN + 127) / 128) * 128;  // 50048
    const int NB = (NN + 255) / 256;   // scan blocks (196 <= 256)
    const int PB = (NN + 3) / 4;       // prep blocks
    const int EB = (E + 255) / 256;    // deg blocks
    const int TB = 1024;               // weight-split blocks (262144/256)
    const int* src = ei;
    const int* dst = ei + E;

    char* p = (char*)d_ws;
    auto alloc = [&](size_t bytes) -> char* {
        char* r = p;
        p += (bytes + 255) & ~(size_t)255;
        return r;
    };
    char* zz = p;
    int*   deg  = (int*)alloc((size_t)NN * 4);
    int*   cur  = (int*)alloc((size_t)NN * 4);
    float* gsum = (float*)alloc(800 * 4);
    size_t zz_bytes = (size_t)(p - zz);
    float* dinv = (float*)alloc((size_t)NN * 4);
    int*   offs = (int*)alloc((size_t)NN * 4);
    int*   bsum = (int*)alloc(1024);
    int*   gid  = (int*)alloc((size_t)NN * 4);
    uint2* epk  = (uint2*)alloc((size_t)E * 8);
    ushort* WT1h = (ushort*)alloc((size_t)512 * 128 * 2);
    ushort* WT1l = (ushort*)alloc((size_t)512 * 128 * 2);
    ushort* WT2h = (ushort*)alloc((size_t)256 * 512 * 2);
    ushort* WT2l = (ushort*)alloc((size_t)256 * 512 * 2);
    ushort* WT3h = (ushort*)alloc((size_t)128 * 256 * 2);
    ushort* WT3l = (ushort*)alloc((size_t)128 * 256 * 2);
    ushort* WT4h = (ushort*)alloc((size_t)256 * 128 * 2);
    ushort* WT4l = (ushort*)alloc((size_t)256 * 128 * 2);
    ushort* xb = (ushort*)alloc((size_t)NN * 128 * 2);
    ushort* P1 = (ushort*)alloc((size_t)MPAD * 128 * 2);
    ushort* H1 = (ushort*)alloc((size_t)MPAD * 512 * 2);
    ushort* T2 = (ushort*)alloc((size_t)MPAD * 256 * 2);
    ushort* H2 = (ushort*)alloc((size_t)MPAD * 256 * 2);
    ushort* T3 = (ushort*)alloc((size_t)MPAD * 128 * 2);
    ushort* H3 = (ushort*)alloc((size_t)MPAD * 128 * 2);
    ushort* P4 = (ushort*)alloc((size_t)MPAD * 128 * 2);

    hipMemsetAsync(zz, 0, zz_bytes, stream);

    k_init<<<PB + EB + TB, 256, 0, stream>>>(
        (const uint*)x, (const uint*)nf, xb, gid, NN, dst, E, deg,
        W1, W2, W3, W4, WT1h, WT1l, WT2h, WT2l, WT3h, WT3l, WT4h, WT4l, PB, EB);
    k_scanA<<<NB, 256, 0, stream>>>(deg, offs, bsum, dinv, NN);
    k_scanB<<<1, 256, 0, stream>>>(bsum, NB);
    k_scanC<<<NB, 256, 0, stream>>>(offs, bsum, NN);
    k_fill<<<EB, 256, 0, stream>>>(src, dst, E, dinv, offs, cur, epk);

    int aggBlocks = MPAD / 8;  // 2 nodes per wave, 4 waves per block
    int mB = MPAD / 128;

    // P1 = agg(xb) -> bf16 [MPAD,128]
    k_agg2<128, false><<<aggBlocks, 256, 0, stream>>>(xb, P1, dinv, offs, deg, epk, nullptr, NN, MPAD);
    // H1 = relu(P1 @ W1 + b1) -> bf16 [MPAD,512]
    k_gemm<true, 1><<<mB * 4, 256, 0, stream>>>(P1, WT1h, WT1l, b1, H1, 512, 128, 4, nullptr, nullptr, 0);
    // T2 = H1 @ W2 -> bf16 [MPAD,256]
    k_gemm<false, 1><<<mB * 2, 256, 0, stream>>>(H1, WT2h, WT2l, nullptr, T2, 256, 512, 2, nullptr, nullptr, 0);
    // H2 = relu(agg(T2) + b2) -> bf16 [MPAD,256]
    k_agg2<256, true><<<aggBlocks, 256, 0, stream>>>(T2, H2, dinv, offs, deg, epk, b2, NN, MPAD);
    // T3 = H2 @ W3 -> bf16 [MPAD,128]
    k_gemm<false, 1><<<mB * 1, 256, 0, stream>>>(H2, WT3h, WT3l, nullptr, T3, 128, 256, 1, nullptr, nullptr, 0);
    // H3 = relu(agg(T3) + b3) -> bf16 [MPAD,128]
    k_agg2<128, true><<<aggBlocks, 256, 0, stream>>>(T3, H3, dinv, offs, deg, epk, b3, NN, MPAD);
    // P4 = agg(H3) -> bf16 [MPAD,128]
    k_agg2<128, false><<<aggBlocks, 256, 0, stream>>>(H3, P4, dinv, offs, deg, epk, nullptr, NN, MPAD);
    // relu(P4 @ W4 + b4) reduced per-group directly into gsum (no H4 tensor)
    k_gemm<true, 2><<<mB * 2, 256, 0, stream>>>(P4, WT4h, WT4l, b4, nullptr, 200, 128, 2, gid, gsum, NN);

    k_final<<<1, 1024, 0, stream>>>(gsum, gid, NN, out);
}